// Round 7
// baseline (8296.447 us; speedup 1.0000x reference)
//
#include <hip/hip_runtime.h>
#include <hip/hip_bf16.h>
#include <math.h>

typedef unsigned short ushort_t;

#define DEV __device__ __forceinline__

DEV float bf2f(ushort_t u) {
  return __uint_as_float(((unsigned int)u) << 16);
}
DEV ushort_t f2bf(float f) {
  unsigned int x = __float_as_uint(f);
  return (ushort_t)((x + 0x7FFFu + ((x >> 16) & 1u)) >> 16);
}

// Fast exact-gelu: Abramowitz-Stegun 7.1.26 erf approx, |err| <= 1.5e-7.
DEV float gelu_f(float x) {
  float z = fabsf(x) * 0.70710678118654752f;
  float t = __builtin_amdgcn_rcpf(1.0f + 0.3275911f * z);
  float p = t * (0.254829592f +
            t * (-0.284496736f +
            t * (1.421413741f +
            t * (-1.453152027f +
            t * 1.061405429f))));
  float e = 1.0f - p * __expf(-z * z);      // erf(|x|/sqrt(2))
  float s = (x >= 0.f) ? e : -e;
  return 0.5f * x * (1.0f + s);
}

using bf16x8 = __attribute__((ext_vector_type(8))) __bf16;
using f32x4  = __attribute__((ext_vector_type(4))) float;

DEV void gload16(const ushort_t* g, ushort_t* l) {
  __builtin_amdgcn_global_load_lds((const __attribute__((address_space(1))) void*)g,
                                   (__attribute__((address_space(3))) void*)l, 16, 0, 0);
}

// Stage a 256-row x 64-col bf16 tile with 512 threads into linear LDS [256][64].
DEV void stage256(const ushort_t* g, int ld, ushort_t* lds, int t) {
  int w = t >> 6;
#pragma unroll
  for (int r = 0; r < 4; ++r) {
    int chunk = r * 512 + t;                       // 2048 chunks of 16B
    const ushort_t* gp = g + (size_t)(chunk >> 3) * ld + (size_t)(chunk & 7) * 8;
    ushort_t* lp = lds + (size_t)(r * 512 + w * 64) * 8;
    gload16(gp, lp);
  }
}

// ============================================================================
// 256x256 2-phase GEMM. 512 threads = 8 waves (2x4); wave tile 128x64.
// Best measured structure for ff1 (K=512): 630 TF effective (r6 counters).
// C = A (MxK,row-major,lda) * B^T, B (NxK,row-major,ldb). K % 64 == 0.
// ============================================================================
template <typename F>
DEV void gemm256_2ph(const ushort_t* A, int lda, const ushort_t* B, int ldb, int K, F&& epi) {
  __shared__ alignas(16) ushort_t As[256 * 64];
  __shared__ alignas(16) ushort_t Bs[256 * 64];
  int t = threadIdx.x;
  int lane = t & 63;
  int w = t >> 6;
  int ur = w >> 2, uc = w & 3;          // 2 x 4 wave grid
  f32x4 acc[8][4];
#pragma unroll
  for (int m = 0; m < 8; ++m)
#pragma unroll
    for (int n = 0; n < 4; ++n) acc[m][n] = (f32x4){0.f, 0.f, 0.f, 0.f};

  for (int kt = 0; kt < K; kt += 64) {
    __syncthreads();
    stage256(A + kt, lda, As, t);
    stage256(B + kt, ldb, Bs, t);
    __syncthreads();
#pragma unroll
    for (int kk = 0; kk < 2; ++kk) {
      int kb = kk * 32 + (lane >> 4) * 8;
      bf16x8 af[8], bfr[4];
#pragma unroll
      for (int m = 0; m < 8; ++m)
        af[m] = *(const bf16x8*)&As[(size_t)(ur * 128 + m * 16 + (lane & 15)) * 64 + kb];
#pragma unroll
      for (int n = 0; n < 4; ++n)
        bfr[n] = *(const bf16x8*)&Bs[(size_t)(uc * 64 + n * 16 + (lane & 15)) * 64 + kb];
#pragma unroll
      for (int m = 0; m < 8; ++m)
#pragma unroll
        for (int n = 0; n < 4; ++n)
          acc[m][n] = __builtin_amdgcn_mfma_f32_16x16x32_bf16(af[m], bfr[n], acc[m][n], 0, 0, 0);
    }
  }
#pragma unroll
  for (int m = 0; m < 8; ++m)
#pragma unroll
    for (int n = 0; n < 4; ++n)
#pragma unroll
      for (int r = 0; r < 4; ++r) {
        int lr = ur * 128 + m * 16 + (lane >> 4) * 4 + r;
        int lc = uc * 64 + n * 16 + (lane & 15);
        epi(lr, lc, acc[m][n][r]);
      }
}

// ============================================================================
// 256x256 8-phase GEMM (T2 swizzle + T3/T4 counted vmcnt + T5 setprio).
// Used for ff2 (K=2048, nk=32). C = A (MxK,row-major) * B^T, B (NxK,row-major).
// ============================================================================
#define MFMA_QUAD(QM, QN)                                                      \
  _Pragma("unroll") for (int m_ = 0; m_ < 4; ++m_)                             \
  _Pragma("unroll") for (int n_ = 0; n_ < 2; ++n_)                             \
  _Pragma("unroll") for (int kk_ = 0; kk_ < 2; ++kk_)                          \
    acc[QM][QN][m_][n_] = __builtin_amdgcn_mfma_f32_16x16x32_bf16(             \
        aF[m_][kk_], bF[QN][n_][kk_], acc[QM][QN][m_][n_], 0, 0, 0);

template <typename F>
DEV void gemm256(const ushort_t* A, int lda, const ushort_t* B, int ldb, int K, F&& epi) {
  __shared__ alignas(16) ushort_t As[2][256 * 64];
  __shared__ alignas(16) ushort_t Bs[2][256 * 64];
  const int tid = threadIdx.x;
  const int lane = tid & 63;
  const int w = tid >> 6;
  const int ur = w >> 2, uc = w & 3;
  const int nk = K >> 6;

  const int c0 = tid, c1 = 512 + tid;
  const int row0 = c0 >> 3, row1 = c1 >> 3;
  const int sw0 = ((c0 & 7) ^ (row0 & 7)) * 8;
  const int sw1 = ((c1 & 7) ^ (row1 & 7)) * 8;
  const ushort_t* Ab0 = A + (size_t)row0 * lda + sw0;
  const ushort_t* Ab1 = A + (size_t)row1 * lda + sw1;
  const ushort_t* Bb0 = B + (size_t)row0 * ldb + sw0;
  const ushort_t* Bb1 = B + (size_t)row1 * ldb + sw1;
  const int ld0 = (0 * 512 + w * 64) * 8;
  const int ld1 = (1 * 512 + w * 64) * 8;

  auto stageA = [&](int t, int hh, int b) {
    const ushort_t* g0 = Ab0 + (size_t)hh * 128 * lda + t * 64;
    const ushort_t* g1 = Ab1 + (size_t)hh * 128 * lda + t * 64;
    ushort_t* l = &As[b][hh * 8192];
    gload16(g0, l + ld0);
    gload16(g1, l + ld1);
  };
  auto stageB = [&](int t, int hh, int b) {
    const ushort_t* g0 = Bb0 + (size_t)hh * 128 * ldb + t * 64;
    const ushort_t* g1 = Bb1 + (size_t)hh * 128 * ldb + t * 64;
    ushort_t* l = &Bs[b][hh * 8192];
    gload16(g0, l + ld0);
    gload16(g1, l + ld1);
  };

  int aoff[4][2], boff[2][2];
#pragma unroll
  for (int m = 0; m < 4; ++m)
#pragma unroll
    for (int kk = 0; kk < 2; ++kk) {
      int row = ur * 64 + m * 16 + (lane & 15);
      int ks = kk * 4 + (lane >> 4);
      aoff[m][kk] = row * 64 + ((ks ^ (lane & 7)) * 8);
    }
#pragma unroll
  for (int n = 0; n < 2; ++n)
#pragma unroll
    for (int kk = 0; kk < 2; ++kk) {
      int row = uc * 32 + n * 16 + (lane & 15);
      int ks = kk * 4 + (lane >> 4);
      boff[n][kk] = row * 64 + ((ks ^ (lane & 7)) * 8);
    }

  f32x4 acc[2][2][4][2];
#pragma unroll
  for (int qm = 0; qm < 2; ++qm)
#pragma unroll
    for (int qn = 0; qn < 2; ++qn)
#pragma unroll
      for (int m = 0; m < 4; ++m)
#pragma unroll
        for (int n = 0; n < 2; ++n) acc[qm][qn][m][n] = (f32x4){0.f, 0.f, 0.f, 0.f};

  stageA(0, 0, 0);
  stageB(0, 0, 0);
  stageB(0, 1, 0);
  stageA(0, 1, 0);
  stageA(1, 0, 1);
  stageB(1, 0, 1);
  asm volatile("s_waitcnt vmcnt(8)" ::: "memory");
  __builtin_amdgcn_s_barrier();

  bf16x8 aF[4][2], bF[2][2][2];

  for (int t = 0; t < nk; ++t) {
    const int b = t & 1;
    const ushort_t* asb = &As[b][0];
    const ushort_t* bsb = &Bs[b][0];
    const int t1 = (t + 1 < nk) ? t + 1 : nk - 1;
    const int t2 = (t + 2 < nk) ? t + 2 : nk - 1;

    // phase 0: quadrant (0,0); stage B1(t+1)
#pragma unroll
    for (int m = 0; m < 4; ++m)
#pragma unroll
      for (int kk = 0; kk < 2; ++kk) aF[m][kk] = *(const bf16x8*)&asb[aoff[m][kk]];
#pragma unroll
    for (int n = 0; n < 2; ++n)
#pragma unroll
      for (int kk = 0; kk < 2; ++kk) bF[0][n][kk] = *(const bf16x8*)&bsb[boff[n][kk]];
    stageB(t1, 1, (t + 1) & 1);
    __builtin_amdgcn_s_barrier();
    asm volatile("s_waitcnt lgkmcnt(0)" ::: "memory");
    __builtin_amdgcn_s_setprio(1);
    MFMA_QUAD(0, 0)
    __builtin_amdgcn_s_setprio(0);
    asm volatile("s_waitcnt vmcnt(8)" ::: "memory");
    __builtin_amdgcn_s_barrier();

    // phase 1: quadrant (0,1); stage A1(t+1)
#pragma unroll
    for (int n = 0; n < 2; ++n)
#pragma unroll
      for (int kk = 0; kk < 2; ++kk) bF[1][n][kk] = *(const bf16x8*)&bsb[boff[n][kk] + 8192];
    stageA(t1, 1, (t + 1) & 1);
    __builtin_amdgcn_s_barrier();
    asm volatile("s_waitcnt lgkmcnt(0)" ::: "memory");
    __builtin_amdgcn_s_setprio(1);
    MFMA_QUAD(0, 1)
    __builtin_amdgcn_s_setprio(0);
    asm volatile("s_waitcnt vmcnt(8)" ::: "memory");
    __builtin_amdgcn_s_barrier();

    // phase 2: quadrant (1,0); stage A0(t+2)
#pragma unroll
    for (int m = 0; m < 4; ++m)
#pragma unroll
      for (int kk = 0; kk < 2; ++kk) aF[m][kk] = *(const bf16x8*)&asb[aoff[m][kk] + 8192];
    stageA(t2, 0, b);
    __builtin_amdgcn_s_barrier();
    asm volatile("s_waitcnt lgkmcnt(0)" ::: "memory");
    __builtin_amdgcn_s_setprio(1);
    MFMA_QUAD(1, 0)
    __builtin_amdgcn_s_setprio(0);
    __builtin_amdgcn_s_barrier();

    // phase 3: quadrant (1,1); stage B0(t+2)
    stageB(t2, 0, b);
    __builtin_amdgcn_s_barrier();
    __builtin_amdgcn_s_setprio(1);
    MFMA_QUAD(1, 1)
    __builtin_amdgcn_s_setprio(0);
    asm volatile("s_waitcnt vmcnt(8)" ::: "memory");
    __builtin_amdgcn_s_barrier();
  }
  asm volatile("s_waitcnt vmcnt(0)" ::: "memory");

#pragma unroll
  for (int qm = 0; qm < 2; ++qm)
#pragma unroll
    for (int qn = 0; qn < 2; ++qn)
#pragma unroll
      for (int m = 0; m < 4; ++m)
#pragma unroll
        for (int n = 0; n < 2; ++n)
#pragma unroll
          for (int r = 0; r < 4; ++r) {
            int lr = qm * 128 + ur * 64 + m * 16 + (lane >> 4) * 4 + r;
            int lc = qn * 128 + uc * 32 + n * 16 + (lane & 15);
            epi(lr, lc, acc[qm][qn][m][n][r]);
          }
}

// ============================================================================
// 128x128 2-phase GEMM — for the small sim/pv GEMMs (proven round-2/4).
// ============================================================================
DEV void stage_tile(const ushort_t* g, int ld, ushort_t* lds, int t) {
  int w = t >> 6;
#pragma unroll
  for (int r = 0; r < 4; ++r) {
    int chunk = r * 256 + t;
    const ushort_t* gp = g + (size_t)(chunk >> 3) * ld + (size_t)(chunk & 7) * 8;
    ushort_t* lp = lds + (size_t)(r * 256 + w * 64) * 8;
    gload16(gp, lp);
  }
}

template <typename F>
DEV void gemm_tile(const ushort_t* A, int lda, const ushort_t* B, int ldb, int K, F&& epi) {
  __shared__ alignas(16) ushort_t As[128 * 64];
  __shared__ alignas(16) ushort_t Bs[128 * 64];
  int t = threadIdx.x;
  int lane = t & 63;
  int w = t >> 6;
  int wr = w >> 1, wc = w & 1;
  f32x4 zero = {0.f, 0.f, 0.f, 0.f};
  f32x4 acc[4][4];
#pragma unroll
  for (int m = 0; m < 4; ++m)
#pragma unroll
    for (int n = 0; n < 4; ++n) acc[m][n] = zero;

  for (int kt = 0; kt < K; kt += 64) {
    __syncthreads();
    stage_tile(A + kt, lda, As, t);
    stage_tile(B + kt, ldb, Bs, t);
    __syncthreads();
#pragma unroll
    for (int kk = 0; kk < 2; ++kk) {
      int kb = kk * 32 + (lane >> 4) * 8;
      bf16x8 af[4], bfr[4];
#pragma unroll
      for (int m = 0; m < 4; ++m)
        af[m] = *(const bf16x8*)&As[(size_t)(wr * 64 + m * 16 + (lane & 15)) * 64 + kb];
#pragma unroll
      for (int n = 0; n < 4; ++n)
        bfr[n] = *(const bf16x8*)&Bs[(size_t)(wc * 64 + n * 16 + (lane & 15)) * 64 + kb];
#pragma unroll
      for (int m = 0; m < 4; ++m)
#pragma unroll
        for (int n = 0; n < 4; ++n)
          acc[m][n] = __builtin_amdgcn_mfma_f32_16x16x32_bf16(af[m], bfr[n], acc[m][n], 0, 0, 0);
    }
  }
#pragma unroll
  for (int m = 0; m < 4; ++m)
#pragma unroll
    for (int n = 0; n < 4; ++n)
#pragma unroll
      for (int r = 0; r < 4; ++r) {
        int lr = wr * 64 + m * 16 + (lane >> 4) * 4 + r;
        int lc = wc * 64 + n * 16 + (lane & 15);
        epi(lr, lc, acc[m][n][r]);
      }
}

// ---------------- FF layer 1: x(512) -> h(2048), 256x256 2ph, fused bias+gelu -> bf16 ----------
__global__ __launch_bounds__(512, 2) void ff1_kernel(
    int g0, const ushort_t* tokens, const ushort_t* levels_bf, const ushort_t* levels_pos,
    const ushort_t* w1_bf, const float* bu_b1, const float* td_b1, ushort_t* h) {
  int g = g0 + blockIdx.z;
  int tm = blockIdx.x, tn = blockIdx.y;
  const ushort_t* A; int lda;
  if (g == 0)      { A = tokens     + (size_t)tm * 256 * 512;                              lda = 512;  }
  else if (g < 6)  { A = levels_bf  + (size_t)tm * 256 * 3072 + (size_t)(g - 1) * 512;     lda = 3072; }
  else             { A = levels_pos + (size_t)tm * 256 * 2560 + (size_t)(g - 6) * 512;     lda = 2560; }
  const ushort_t* W = w1_bf + (size_t)g * 2048 * 512 + (size_t)tn * 256 * 512;
  const float* bias = (g < 6) ? (bu_b1 + (size_t)g * 2048) : (td_b1 + (size_t)(g - 6) * 2048);
  ushort_t* out = h + ((size_t)(g - g0) * 4096 + (size_t)tm * 256) * 2048 + (size_t)tn * 256;
  gemm256_2ph(A, lda, W, 512, 512, [&](int lr, int lc, float v) {
    float x = v + bias[tn * 256 + lc];
    out[(size_t)lr * 2048 + lc] = f2bf(gelu_f(x));
  });
}

// ---------------- FF layer 2: h(2048) -> 512, 8-phase, fused bias ----------------
// With tdbuf != null: bu groups (g<6) accumulate into levels; td groups WRITE tdbuf
// (each index once -> no race, any group mix in one launch is safe).
// With tdbuf == null: all groups += levels; caller must keep g and g+6 apart.
__global__ __launch_bounds__(512, 2) void ff2_kernel(
    int g0, const ushort_t* h, const ushort_t* w2_bf, const float* bu_b2, const float* td_b2,
    float* levels, float* tdbuf) {
  int g = g0 + blockIdx.z;
  int tm = blockIdx.x, tn = blockIdx.y;
  const ushort_t* A = h + ((size_t)(g - g0) * 4096 + (size_t)tm * 256) * 2048;
  const ushort_t* W = w2_bf + (size_t)g * 512 * 2048 + (size_t)tn * 256 * 2048;
  int l = (g < 6) ? g : (g - 6);
  const float* bias = (g < 6) ? (bu_b2 + (size_t)g * 512) : (td_b2 + (size_t)(g - 6) * 512);
  bool to_td = (g >= 6) && (tdbuf != nullptr);
  gemm256(A, 2048, W, 2048, 2048, [&](int lr, int lc, float v) {
    int bn = tm * 256 + lr;
    int d  = tn * 256 + lc;
    float r = v + bias[d];
    if (to_td) tdbuf[((size_t)bn * 5 + l) * 512 + d] = r;
    else       levels[((size_t)bn * 6 + l) * 512 + d] += r;
  });
}

// ---------------- SIM: Gram(levels) with fused inv-norm column scale + diag mask -> bf16 --------
__global__ __launch_bounds__(256) void sim_kernel(const ushort_t* levels_bf, const float* invn,
                                                  ushort_t* simattn) {
  int bl = blockIdx.z; int tm = blockIdx.x, tn = blockIdx.y;
  int b = bl / 6, l = bl % 6;
  const ushort_t* A = levels_bf + ((size_t)(b * 256 + tm * 128) * 6 + l) * 512;
  const ushort_t* B = levels_bf + ((size_t)(b * 256 + tn * 128) * 6 + l) * 512;
  const float* inv = invn + (size_t)bl * 256;
  ushort_t* out = simattn + ((size_t)bl * 256 + tm * 128) * 256 + (size_t)tn * 128;
  gemm_tile(A, 3072, B, 3072, 512, [&](int lr, int lc, float v) {
    int i = tm * 128 + lr, j = tn * 128 + lc;
    float s = (i == j) ? -0.0005f : v * inv[j] * 0.044194173824159216f;
    out[(size_t)lr * 256 + lc] = f2bf(s);
  });
}

// ---------------- softmax over 256-wide rows of simattn, in place (bf16) ----------------
__global__ __launch_bounds__(256) void softmax_kernel(ushort_t* simattn) {
  int row = blockIdx.x, t = threadIdx.x;
  __shared__ float red[256];
  float x = bf2f(simattn[(size_t)row * 256 + t]);
  red[t] = x;
  __syncthreads();
  for (int s = 128; s > 0; s >>= 1) { if (t < s) red[t] = fmaxf(red[t], red[t + s]); __syncthreads(); }
  float mx = red[0];
  __syncthreads();
  float e = __expf(x - mx);
  red[t] = e;
  __syncthreads();
  for (int s = 128; s > 0; s >>= 1) { if (t < s) red[t] += red[t + s]; __syncthreads(); }
  float den = red[0];
  simattn[(size_t)row * 256 + t] = f2bf(e / den);
}

// ---------------- PV: levels += attn * levels_snapshot (in place, f32) ----------------
__global__ __launch_bounds__(256) void pv_kernel(const ushort_t* attn, const ushort_t* levelsT,
                                                 float* levels) {
  int bl = blockIdx.z; int tm = blockIdx.x, tn = blockIdx.y;
  int b = bl / 6, l = bl % 6;
  const ushort_t* A = attn + (size_t)bl * 256 * 256 + (size_t)tm * 128 * 256;
  const ushort_t* B = levelsT + ((size_t)bl * 512 + (size_t)tn * 128) * 256;
  gemm_tile(A, 256, B, 256, 256, [&](int lr, int lc, float v) {
    int n = tm * 128 + lr;
    int d = tn * 128 + lc;
    size_t idx = (((size_t)b * 256 + n) * 6 + l) * 512 + d;
    levels[idx] += v;
  });
}

// ---- prep: fold tdbuf (if used), apply contrib scale, emit bf16 copies + inv-norms ----
__global__ __launch_bounds__(128) void prep_kernel(float* levels, const float* pos_emb,
                                                   ushort_t* levels_bf, ushort_t* levels_pos,
                                                   float* invn, const float* tdbuf, int apply) {
  int bid = blockIdx.x;           // (b*256+n)*6 + l
  int l = bid % 6;
  int bn = bid / 6;
  int n = bn & 255, b = bn >> 8;
  int t = threadIdx.x;
  float4 lv = *(const float4*)&levels[(size_t)bid * 512 + t * 4];
  if (apply) {
    if (tdbuf != nullptr && l < 5) {
      float4 td = *(const float4*)&tdbuf[((size_t)bn * 5 + l) * 512 + t * 4];
      lv.x += td.x; lv.y += td.y; lv.z += td.z; lv.w += td.w;
    }
    float rc = (l == 5) ? (1.0f / 3.0f) : 0.25f;
    lv.x *= rc; lv.y *= rc; lv.z *= rc; lv.w *= rc;
    *(float4*)&levels[(size_t)bid * 512 + t * 4] = lv;   // write back scaled state
  }
  float ss = lv.x * lv.x + lv.y * lv.y + lv.z * lv.z + lv.w * lv.w;
#pragma unroll
  for (int off = 32; off > 0; off >>= 1) ss += __shfl_down(ss, off);
  __shared__ float s2[2];
  if ((t & 63) == 0) s2[t >> 6] = ss;
  __syncthreads();
  if (t == 0) {
    float tot = s2[0] + s2[1];
    invn[(size_t)(b * 6 + l) * 256 + n] = 1.0f / fmaxf(sqrtf(tot), 1e-12f);
  }
  ushort4 o;
  o.x = f2bf(lv.x); o.y = f2bf(lv.y); o.z = f2bf(lv.z); o.w = f2bf(lv.w);
  *(ushort4*)&levels_bf[(size_t)bid * 512 + t * 4] = o;
  if (l >= 1) {
    float4 pu = *(const float4*)&pos_emb[(size_t)n * 512 + t * 4];
    ushort4 op;
    op.x = f2bf(lv.x + pu.x);
    op.y = f2bf(lv.y + pu.y);
    op.z = f2bf(lv.z + pu.z);
    op.w = f2bf(lv.w + pu.w);
    *(ushort4*)&levels_pos[((size_t)bn * 5 + (l - 1)) * 512 + t * 4] = op;
  }
}

// ---------------- transpose: levels f32 (b,n,l,d) -> levelsT bf16 (b,l,d,n) ----------------
__global__ __launch_bounds__(256) void transpose_kernel(const float* levels, ushort_t* levelsT) {
  int bl = blockIdx.z; int b = bl / 6, l = bl % 6;
  int n0 = blockIdx.y * 64, d0 = blockIdx.x * 64;
  __shared__ ushort_t tile[64][72];
  int t = threadIdx.x;
#pragma unroll
  for (int rr = 0; rr < 2; ++rr) {
    int c = t + rr * 256;
    int r = c >> 3, c8 = (c & 7) * 8;
    const float* src = &levels[(((size_t)(b * 256 + n0 + r)) * 6 + l) * 512 + d0 + c8];
    float4 v0 = *(const float4*)src;
    float4 v1 = *(const float4*)(src + 4);
    tile[r][c8 + 0] = f2bf(v0.x); tile[r][c8 + 1] = f2bf(v0.y);
    tile[r][c8 + 2] = f2bf(v0.z); tile[r][c8 + 3] = f2bf(v0.w);
    tile[r][c8 + 4] = f2bf(v1.x); tile[r][c8 + 5] = f2bf(v1.y);
    tile[r][c8 + 6] = f2bf(v1.z); tile[r][c8 + 7] = f2bf(v1.w);
  }
  __syncthreads();
#pragma unroll
  for (int rr = 0; rr < 2; ++rr) {
    int c = t + rr * 256;
    int dr = c >> 3, n8 = (c & 7) * 8;
    ushort4 o0, o1;
    o0.x = tile[n8 + 0][dr]; o0.y = tile[n8 + 1][dr]; o0.z = tile[n8 + 2][dr]; o0.w = tile[n8 + 3][dr];
    o1.x = tile[n8 + 4][dr]; o1.y = tile[n8 + 5][dr]; o1.z = tile[n8 + 6][dr]; o1.w = tile[n8 + 7][dr];
    ushort_t* dst = &levelsT[((size_t)bl * 512 + d0 + dr) * 256 + n0 + n8];
    *(ushort4*)dst = o0;
    *(ushort4*)(dst + 4) = o1;
  }
}

// ---------------- patch embed: img(f32) -> tokens bf16 (4096 x 512) ----------------
__global__ __launch_bounds__(256) void tokens_kernel(const float* img, const float* ttw,
                                                     const float* ttb, ushort_t* tokens) {
  int token = blockIdx.x;
  int b = token >> 8, n = token & 255;
  int ph = n >> 4, pw = n & 15;
  __shared__ float patch[196];
  int t = threadIdx.x;
  if (t < 196) {
    int r = t / 14, cc = t % 14;
    patch[t] = img[(size_t)b * 50176 + (size_t)(ph * 14 + r) * 224 + pw * 14 + cc];
  }
  __syncthreads();
  float a0 = ttb[t];
  float a1 = ttb[t + 256];
  for (int k = 0; k < 196; ++k) {
    float p = patch[k];
    a0 += p * ttw[(size_t)k * 512 + t];
    a1 += p * ttw[(size_t)k * 512 + t + 256];
  }
  tokens[(size_t)token * 512 + t]       = f2bf(a0);
  tokens[(size_t)token * 512 + t + 256] = f2bf(a1);
}

// ---------------- init: broadcast init_levels(f32) -> levels f32 (d_out) ----------------
__global__ void init_kernel(const float* init_levels, float* levels) {
  size_t i4 = (size_t)blockIdx.x * 256 + threadIdx.x;
  size_t e0 = i4 * 4;
  int idx = (int)(e0 % 3072);
  *(float4*)&levels[e0] = *(const float4*)&init_levels[idx];
}

// ---------------- final scale: fold tdbuf (if used) + contrib division ----------------
__global__ void scale_kernel(float* levels, const float* tdbuf) {
  size_t i4 = (size_t)blockIdx.x * 256 + threadIdx.x;
  size_t e0 = i4 * 4;
  int l = (int)((e0 >> 9) % 6);
  size_t bn = e0 / 3072;
  int d = (int)(e0 & 511);
  float4 a = *(const float4*)&levels[e0];
  if (tdbuf != nullptr && l < 5) {
    float4 td = *(const float4*)&tdbuf[((size_t)bn * 5 + l) * 512 + d];
    a.x += td.x; a.y += td.y; a.z += td.z; a.w += td.w;
  }
  float rc = (l == 5) ? (1.0f / 3.0f) : 0.25f;
  float4 o = {a.x * rc, a.y * rc, a.z * rc, a.w * rc};
  *(float4*)&levels[e0] = o;
}

// ---------------- cvt: f32 -> bf16, 4 elems/thread ----------------
__global__ void cvt_kernel(const float* src, ushort_t* dst, int n4) {
  int i = blockIdx.x * 256 + threadIdx.x;
  if (i >= n4) return;
  float4 v = ((const float4*)src)[i];
  ushort4 o;
  o.x = f2bf(v.x); o.y = f2bf(v.y); o.z = f2bf(v.z); o.w = f2bf(v.w);
  ((ushort4*)dst)[i] = o;
}

extern "C" void kernel_launch(void* const* d_in, const int* in_sizes, int n_in,
                              void* d_out, int out_size, void* d_ws, size_t ws_size,
                              hipStream_t stream) {
  const float* img    = (const float*)d_in[0];
  const float* ttw    = (const float*)d_in[1];
  const float* ttb    = (const float*)d_in[2];
  const float* pos    = (const float*)d_in[3];
  const float* initlv = (const float*)d_in[4];
  const float* bu_w1  = (const float*)d_in[5];
  const float* bu_b1  = (const float*)d_in[6];
  const float* bu_w2  = (const float*)d_in[7];
  const float* bu_b2  = (const float*)d_in[8];
  const float* td_w1  = (const float*)d_in[9];
  const float* td_b1  = (const float*)d_in[10];
  const float* td_w2  = (const float*)d_in[11];
  const float* td_b2  = (const float*)d_in[12];

  float* levels = (float*)d_out;   // (b,n,6,512) f32 state lives in d_out

  const size_t HB = 16777216ull;   // bytes per h group (4096x2048 bf16)
  const size_t TDB = 10485760ull * 4;  // tdbuf (b,n,5,512) f32 = 41.9 MB

  char* p = (char*)d_ws;
  auto alloc = [&](size_t bytes) { char* r = p; p += (bytes + 255) & ~(size_t)255; return r; };
  float*    invn       = (float*)alloc(24576ull * 4);
  ushort_t* tokens     = (ushort_t*)alloc(2097152ull * 2);
  ushort_t* levels_bf  = (ushort_t*)alloc(12582912ull * 2);
  ushort_t* levels_pos = (ushort_t*)alloc(10485760ull * 2);
  ushort_t* levelsT    = (ushort_t*)alloc(12582912ull * 2);
  ushort_t* simattn    = (ushort_t*)alloc(6291456ull * 2);
  ushort_t* w1_bf      = (ushort_t*)alloc(11534336ull * 2);
  ushort_t* w2_bf      = (ushort_t*)alloc(11534336ull * 2);
  size_t used = (size_t)(p - (char*)d_ws);

  // tdbuf only if it and >=1 h group still fit; else fall back to race-guard split.
  float* tdbuf = nullptr;
  if (used + TDB + HB + 512 <= ws_size) tdbuf = (float*)alloc(TDB);
  used = (size_t)(p - (char*)d_ws);
  if (used + HB > ws_size) return;                   // can't fit even 1-group h
  int hgroups = (int)((ws_size - used) / HB);
  int hcap = tdbuf ? 11 : 6;                         // no-tdbuf: contiguous<=6 is race-free
  if (hgroups > hcap) hgroups = hcap;
  ushort_t* h = (ushort_t*)alloc((size_t)hgroups * HB);

  cvt_kernel<<<6144, 256, 0, stream>>>(bu_w1, w1_bf, 1572864);
  cvt_kernel<<<5120, 256, 0, stream>>>(td_w1, w1_bf + 6291456ull, 1310720);
  cvt_kernel<<<6144, 256, 0, stream>>>(bu_w2, w2_bf, 1572864);
  cvt_kernel<<<5120, 256, 0, stream>>>(td_w2, w2_bf + 6291456ull, 1310720);
  tokens_kernel<<<4096, 256, 0, stream>>>(img, ttw, ttb, tokens);
  init_kernel<<<12288, 256, 0, stream>>>(initlv, levels);

  for (int it = 0; it < 12; ++it) {
    // previous iteration's td contribution + contrib scale fold into prep (apply=1)
    prep_kernel<<<24576, 128, 0, stream>>>(levels, pos, levels_bf, levels_pos, invn,
                                           tdbuf, it > 0 ? 1 : 0);
    transpose_kernel<<<dim3(8, 4, 96), 256, 0, stream>>>(levels, levelsT);
    sim_kernel<<<dim3(2, 2, 96), 256, 0, stream>>>(levels_bf, invn, simattn);
    softmax_kernel<<<24576, 256, 0, stream>>>(simattn);
    pv_kernel<<<dim3(2, 4, 96), 256, 0, stream>>>(simattn, levelsT, levels);
    for (int g0 = 0; g0 < 11; g0 += hgroups) {
      int gn = 11 - g0 < hgroups ? 11 - g0 : hgroups;
      ff1_kernel<<<dim3(16, 8, gn), 512, 0, stream>>>(g0, tokens, levels_bf, levels_pos,
                                                      w1_bf, bu_b1, td_b1, h);
      ff2_kernel<<<dim3(16, 2, gn), 512, 0, stream>>>(g0, h, w2_bf, bu_b2, td_b2,
                                                      levels, tdbuf);
    }
  }
  scale_kernel<<<12288, 256, 0, stream>>>(levels, tdbuf);  // final fold + contrib division
}

// Round 8
// 6929.438 us; speedup vs baseline: 1.1973x; 1.1973x over previous
//
#include <hip/hip_runtime.h>
#include <hip/hip_bf16.h>
#include <math.h>

typedef unsigned short ushort_t;

#define DEV __device__ __forceinline__

DEV float bf2f(ushort_t u) {
  return __uint_as_float(((unsigned int)u) << 16);
}
DEV ushort_t f2bf(float f) {
  unsigned int x = __float_as_uint(f);
  return (ushort_t)((x + 0x7FFFu + ((x >> 16) & 1u)) >> 16);
}

// Fast exact-gelu: Abramowitz-Stegun 7.1.26 erf approx, |err| <= 1.5e-7.
DEV float gelu_f(float x) {
  float z = fabsf(x) * 0.70710678118654752f;
  float t = __builtin_amdgcn_rcpf(1.0f + 0.3275911f * z);
  float p = t * (0.254829592f +
            t * (-0.284496736f +
            t * (1.421413741f +
            t * (-1.453152027f +
            t * 1.061405429f))));
  float e = 1.0f - p * __expf(-z * z);      // erf(|x|/sqrt(2))
  float s = (x >= 0.f) ? e : -e;
  return 0.5f * x * (1.0f + s);
}

using bf16x8 = __attribute__((ext_vector_type(8))) __bf16;
using f32x4  = __attribute__((ext_vector_type(4))) float;

DEV void gload16(const ushort_t* g, ushort_t* l) {
  __builtin_amdgcn_global_load_lds((const __attribute__((address_space(1))) void*)g,
                                   (__attribute__((address_space(3))) void*)l, 16, 0, 0);
}

// Stage a 128-row x 64-col bf16 tile (row-major, ld elems) into linear LDS, 256 threads.
DEV void stage_tile(const ushort_t* g, int ld, ushort_t* lds, int t) {
  int w = t >> 6;
#pragma unroll
  for (int r = 0; r < 4; ++r) {
    int chunk = r * 256 + t;
    const ushort_t* gp = g + (size_t)(chunk >> 3) * ld + (size_t)(chunk & 7) * 8;
    ushort_t* lp = lds + (size_t)(r * 256 + w * 64) * 8;
    gload16(gp, lp);
  }
}

// Stage a 256-row x 64-col bf16 tile into linear LDS [256][64], 256 threads.
DEV void stage256_256t(const ushort_t* g, int ld, ushort_t* lds, int t) {
  int w = t >> 6;
#pragma unroll
  for (int r = 0; r < 8; ++r) {
    int chunk = r * 256 + t;                       // 2048 chunks of 16B
    const ushort_t* gp = g + (size_t)(chunk >> 3) * ld + (size_t)(chunk & 7) * 8;
    ushort_t* lp = lds + (size_t)(r * 256 + w * 64) * 8;
    gload16(gp, lp);
  }
}

// ============================================================================
// 128x256 2-phase GEMM for ff1 (short K). 256 threads = 4 waves; each wave
// computes the full 128 rows x a 64-col slice -> 64 MFMA/wave per barrier
// (2x the 128x128 tile) while keeping 256-thr blocks (2 blocks/CU resident).
// C = A (128xK,row-major,lda) * B^T, B (256xK,row-major,ldb). K % 64 == 0.
// ============================================================================
template <typename F>
DEV void gemm128x256(const ushort_t* A, int lda, const ushort_t* B, int ldb, int K, F&& epi) {
  __shared__ alignas(16) ushort_t As[128 * 64];   // 16 KB
  __shared__ alignas(16) ushort_t Bs[256 * 64];   // 32 KB
  int t = threadIdx.x;
  int lane = t & 63;
  int w = t >> 6;                    // 0..3: 64-col slice of the 256-wide tile
  f32x4 acc[8][4];
#pragma unroll
  for (int m = 0; m < 8; ++m)
#pragma unroll
    for (int n = 0; n < 4; ++n) acc[m][n] = (f32x4){0.f, 0.f, 0.f, 0.f};

  for (int kt = 0; kt < K; kt += 64) {
    __syncthreads();
    stage_tile(A + kt, lda, As, t);
    stage256_256t(B + kt, ldb, Bs, t);
    __syncthreads();
#pragma unroll
    for (int kk = 0; kk < 2; ++kk) {
      int kb = kk * 32 + (lane >> 4) * 8;
      bf16x8 af[8], bfr[4];
#pragma unroll
      for (int m = 0; m < 8; ++m)
        af[m] = *(const bf16x8*)&As[(size_t)(m * 16 + (lane & 15)) * 64 + kb];
#pragma unroll
      for (int n = 0; n < 4; ++n)
        bfr[n] = *(const bf16x8*)&Bs[(size_t)(w * 64 + n * 16 + (lane & 15)) * 64 + kb];
#pragma unroll
      for (int m = 0; m < 8; ++m)
#pragma unroll
        for (int n = 0; n < 4; ++n)
          acc[m][n] = __builtin_amdgcn_mfma_f32_16x16x32_bf16(af[m], bfr[n], acc[m][n], 0, 0, 0);
    }
  }
#pragma unroll
  for (int m = 0; m < 8; ++m)
#pragma unroll
    for (int n = 0; n < 4; ++n)
#pragma unroll
      for (int r = 0; r < 4; ++r) {
        int lr = m * 16 + (lane >> 4) * 4 + r;
        int lc = w * 64 + n * 16 + (lane & 15);
        epi(lr, lc, acc[m][n][r]);
      }
}

// ============================================================================
// 256x256 8-phase GEMM (T2 swizzle + T3/T4 counted vmcnt + T5 setprio).
// Used for ff2 (K=2048, nk=32). C = A (MxK,row-major) * B^T, B (NxK,row-major).
// ============================================================================
#define MFMA_QUAD(QM, QN)                                                      \
  _Pragma("unroll") for (int m_ = 0; m_ < 4; ++m_)                             \
  _Pragma("unroll") for (int n_ = 0; n_ < 2; ++n_)                             \
  _Pragma("unroll") for (int kk_ = 0; kk_ < 2; ++kk_)                          \
    acc[QM][QN][m_][n_] = __builtin_amdgcn_mfma_f32_16x16x32_bf16(             \
        aF[m_][kk_], bF[QN][n_][kk_], acc[QM][QN][m_][n_], 0, 0, 0);

template <typename F>
DEV void gemm256(const ushort_t* A, int lda, const ushort_t* B, int ldb, int K, F&& epi) {
  __shared__ alignas(16) ushort_t As[2][256 * 64];
  __shared__ alignas(16) ushort_t Bs[2][256 * 64];
  const int tid = threadIdx.x;
  const int lane = tid & 63;
  const int w = tid >> 6;
  const int ur = w >> 2, uc = w & 3;
  const int nk = K >> 6;

  const int c0 = tid, c1 = 512 + tid;
  const int row0 = c0 >> 3, row1 = c1 >> 3;
  const int sw0 = ((c0 & 7) ^ (row0 & 7)) * 8;
  const int sw1 = ((c1 & 7) ^ (row1 & 7)) * 8;
  const ushort_t* Ab0 = A + (size_t)row0 * lda + sw0;
  const ushort_t* Ab1 = A + (size_t)row1 * lda + sw1;
  const ushort_t* Bb0 = B + (size_t)row0 * ldb + sw0;
  const ushort_t* Bb1 = B + (size_t)row1 * ldb + sw1;
  const int ld0 = (0 * 512 + w * 64) * 8;
  const int ld1 = (1 * 512 + w * 64) * 8;

  auto stageA = [&](int t, int hh, int b) {
    const ushort_t* g0 = Ab0 + (size_t)hh * 128 * lda + t * 64;
    const ushort_t* g1 = Ab1 + (size_t)hh * 128 * lda + t * 64;
    ushort_t* l = &As[b][hh * 8192];
    gload16(g0, l + ld0);
    gload16(g1, l + ld1);
  };
  auto stageB = [&](int t, int hh, int b) {
    const ushort_t* g0 = Bb0 + (size_t)hh * 128 * ldb + t * 64;
    const ushort_t* g1 = Bb1 + (size_t)hh * 128 * ldb + t * 64;
    ushort_t* l = &Bs[b][hh * 8192];
    gload16(g0, l + ld0);
    gload16(g1, l + ld1);
  };

  int aoff[4][2], boff[2][2];
#pragma unroll
  for (int m = 0; m < 4; ++m)
#pragma unroll
    for (int kk = 0; kk < 2; ++kk) {
      int row = ur * 64 + m * 16 + (lane & 15);
      int ks = kk * 4 + (lane >> 4);
      aoff[m][kk] = row * 64 + ((ks ^ (lane & 7)) * 8);
    }
#pragma unroll
  for (int n = 0; n < 2; ++n)
#pragma unroll
    for (int kk = 0; kk < 2; ++kk) {
      int row = uc * 32 + n * 16 + (lane & 15);
      int ks = kk * 4 + (lane >> 4);
      boff[n][kk] = row * 64 + ((ks ^ (lane & 7)) * 8);
    }

  f32x4 acc[2][2][4][2];
#pragma unroll
  for (int qm = 0; qm < 2; ++qm)
#pragma unroll
    for (int qn = 0; qn < 2; ++qn)
#pragma unroll
      for (int m = 0; m < 4; ++m)
#pragma unroll
        for (int n = 0; n < 2; ++n) acc[qm][qn][m][n] = (f32x4){0.f, 0.f, 0.f, 0.f};

  stageA(0, 0, 0);
  stageB(0, 0, 0);
  stageB(0, 1, 0);
  stageA(0, 1, 0);
  stageA(1, 0, 1);
  stageB(1, 0, 1);
  asm volatile("s_waitcnt vmcnt(8)" ::: "memory");
  __builtin_amdgcn_s_barrier();

  bf16x8 aF[4][2], bF[2][2][2];

  for (int t = 0; t < nk; ++t) {
    const int b = t & 1;
    const ushort_t* asb = &As[b][0];
    const ushort_t* bsb = &Bs[b][0];
    const int t1 = (t + 1 < nk) ? t + 1 : nk - 1;
    const int t2 = (t + 2 < nk) ? t + 2 : nk - 1;

    // phase 0: quadrant (0,0); stage B1(t+1)
#pragma unroll
    for (int m = 0; m < 4; ++m)
#pragma unroll
      for (int kk = 0; kk < 2; ++kk) aF[m][kk] = *(const bf16x8*)&asb[aoff[m][kk]];
#pragma unroll
    for (int n = 0; n < 2; ++n)
#pragma unroll
      for (int kk = 0; kk < 2; ++kk) bF[0][n][kk] = *(const bf16x8*)&bsb[boff[n][kk]];
    stageB(t1, 1, (t + 1) & 1);
    __builtin_amdgcn_s_barrier();
    asm volatile("s_waitcnt lgkmcnt(0)" ::: "memory");
    __builtin_amdgcn_s_setprio(1);
    MFMA_QUAD(0, 0)
    __builtin_amdgcn_s_setprio(0);
    asm volatile("s_waitcnt vmcnt(8)" ::: "memory");
    __builtin_amdgcn_s_barrier();

    // phase 1: quadrant (0,1); stage A1(t+1)
#pragma unroll
    for (int n = 0; n < 2; ++n)
#pragma unroll
      for (int kk = 0; kk < 2; ++kk) bF[1][n][kk] = *(const bf16x8*)&bsb[boff[n][kk] + 8192];
    stageA(t1, 1, (t + 1) & 1);
    __builtin_amdgcn_s_barrier();
    asm volatile("s_waitcnt lgkmcnt(0)" ::: "memory");
    __builtin_amdgcn_s_setprio(1);
    MFMA_QUAD(0, 1)
    __builtin_amdgcn_s_setprio(0);
    asm volatile("s_waitcnt vmcnt(8)" ::: "memory");
    __builtin_amdgcn_s_barrier();

    // phase 2: quadrant (1,0); stage A0(t+2)
#pragma unroll
    for (int m = 0; m < 4; ++m)
#pragma unroll
      for (int kk = 0; kk < 2; ++kk) aF[m][kk] = *(const bf16x8*)&asb[aoff[m][kk] + 8192];
    stageA(t2, 0, b);
    __builtin_amdgcn_s_barrier();
    asm volatile("s_waitcnt lgkmcnt(0)" ::: "memory");
    __builtin_amdgcn_s_setprio(1);
    MFMA_QUAD(1, 0)
    __builtin_amdgcn_s_setprio(0);
    __builtin_amdgcn_s_barrier();

    // phase 3: quadrant (1,1); stage B0(t+2)
    stageB(t2, 0, b);
    __builtin_amdgcn_s_barrier();
    __builtin_amdgcn_s_setprio(1);
    MFMA_QUAD(1, 1)
    __builtin_amdgcn_s_setprio(0);
    asm volatile("s_waitcnt vmcnt(8)" ::: "memory");
    __builtin_amdgcn_s_barrier();
  }
  asm volatile("s_waitcnt vmcnt(0)" ::: "memory");

#pragma unroll
  for (int qm = 0; qm < 2; ++qm)
#pragma unroll
    for (int qn = 0; qn < 2; ++qn)
#pragma unroll
      for (int m = 0; m < 4; ++m)
#pragma unroll
        for (int n = 0; n < 2; ++n)
#pragma unroll
          for (int r = 0; r < 4; ++r) {
            int lr = qm * 128 + ur * 64 + m * 16 + (lane >> 4) * 4 + r;
            int lc = qn * 128 + uc * 32 + n * 16 + (lane & 15);
            epi(lr, lc, acc[qm][qn][m][n][r]);
          }
}

// ============================================================================
// 128x128 2-phase GEMM — for the small sim/pv GEMMs (proven round-2/4).
// ============================================================================
template <typename F>
DEV void gemm_tile(const ushort_t* A, int lda, const ushort_t* B, int ldb, int K, F&& epi) {
  __shared__ alignas(16) ushort_t As[128 * 64];
  __shared__ alignas(16) ushort_t Bs[128 * 64];
  int t = threadIdx.x;
  int lane = t & 63;
  int w = t >> 6;
  int wr = w >> 1, wc = w & 1;
  f32x4 zero = {0.f, 0.f, 0.f, 0.f};
  f32x4 acc[4][4];
#pragma unroll
  for (int m = 0; m < 4; ++m)
#pragma unroll
    for (int n = 0; n < 4; ++n) acc[m][n] = zero;

  for (int kt = 0; kt < K; kt += 64) {
    __syncthreads();
    stage_tile(A + kt, lda, As, t);
    stage_tile(B + kt, ldb, Bs, t);
    __syncthreads();
#pragma unroll
    for (int kk = 0; kk < 2; ++kk) {
      int kb = kk * 32 + (lane >> 4) * 8;
      bf16x8 af[4], bfr[4];
#pragma unroll
      for (int m = 0; m < 4; ++m)
        af[m] = *(const bf16x8*)&As[(size_t)(wr * 64 + m * 16 + (lane & 15)) * 64 + kb];
#pragma unroll
      for (int n = 0; n < 4; ++n)
        bfr[n] = *(const bf16x8*)&Bs[(size_t)(wc * 64 + n * 16 + (lane & 15)) * 64 + kb];
#pragma unroll
      for (int m = 0; m < 4; ++m)
#pragma unroll
        for (int n = 0; n < 4; ++n)
          acc[m][n] = __builtin_amdgcn_mfma_f32_16x16x32_bf16(af[m], bfr[n], acc[m][n], 0, 0, 0);
    }
  }
#pragma unroll
  for (int m = 0; m < 4; ++m)
#pragma unroll
    for (int n = 0; n < 4; ++n)
#pragma unroll
      for (int r = 0; r < 4; ++r) {
        int lr = wr * 64 + m * 16 + (lane >> 4) * 4 + r;
        int lc = wc * 64 + n * 16 + (lane & 15);
        epi(lr, lc, acc[m][n][r]);
      }
}

// ---------------- FF layer 1: x(512) -> h(2048), 128x256 2ph, fused bias+gelu -> bf16 ----------
__global__ __launch_bounds__(256) void ff1_kernel(
    int g0, const ushort_t* tokens, const ushort_t* levels_bf, const ushort_t* levels_pos,
    const ushort_t* w1_bf, const float* bu_b1, const float* td_b1, ushort_t* h) {
  int g = g0 + blockIdx.z;
  int tm = blockIdx.x, tn = blockIdx.y;
  const ushort_t* A; int lda;
  if (g == 0)      { A = tokens     + (size_t)tm * 128 * 512;                              lda = 512;  }
  else if (g < 6)  { A = levels_bf  + (size_t)tm * 128 * 3072 + (size_t)(g - 1) * 512;     lda = 3072; }
  else             { A = levels_pos + (size_t)tm * 128 * 2560 + (size_t)(g - 6) * 512;     lda = 2560; }
  const ushort_t* W = w1_bf + (size_t)g * 2048 * 512 + (size_t)tn * 256 * 512;
  const float* bias = (g < 6) ? (bu_b1 + (size_t)g * 2048) : (td_b1 + (size_t)(g - 6) * 2048);
  ushort_t* out = h + ((size_t)(g - g0) * 4096 + (size_t)tm * 128) * 2048 + (size_t)tn * 256;
  gemm128x256(A, lda, W, 512, 512, [&](int lr, int lc, float v) {
    float x = v + bias[tn * 256 + lc];
    out[(size_t)lr * 2048 + lc] = f2bf(gelu_f(x));
  });
}

// ---------------- FF layer 2: h(2048) -> 512, 8-phase, fused bias, accumulate into levels -------
// RACE GUARD: one ff2 launch must never contain both group g and g+6 (both
// accumulate the SAME level l). Contiguous ranges of length <= 6 are safe.
__global__ __launch_bounds__(512, 2) void ff2_kernel(
    int g0, const ushort_t* h, const ushort_t* w2_bf, const float* bu_b2, const float* td_b2,
    float* levels) {
  int g = g0 + blockIdx.z;
  int tm = blockIdx.x, tn = blockIdx.y;
  const ushort_t* A = h + ((size_t)(g - g0) * 4096 + (size_t)tm * 256) * 2048;
  const ushort_t* W = w2_bf + (size_t)g * 512 * 2048 + (size_t)tn * 256 * 2048;
  int l = (g < 6) ? g : (g - 6);
  const float* bias = (g < 6) ? (bu_b2 + (size_t)g * 512) : (td_b2 + (size_t)(g - 6) * 512);
  gemm256(A, 2048, W, 2048, 2048, [&](int lr, int lc, float v) {
    int bn = tm * 256 + lr;
    int d  = tn * 256 + lc;
    size_t idx = ((size_t)bn * 6 + l) * 512 + d;
    levels[idx] += v + bias[d];
  });
}

// ---------------- SIM: Gram(levels) with fused inv-norm column scale + diag mask -> bf16 --------
__global__ __launch_bounds__(256) void sim_kernel(const ushort_t* levels_bf, const float* invn,
                                                  ushort_t* simattn) {
  int bl = blockIdx.z; int tm = blockIdx.x, tn = blockIdx.y;
  int b = bl / 6, l = bl % 6;
  const ushort_t* A = levels_bf + ((size_t)(b * 256 + tm * 128) * 6 + l) * 512;
  const ushort_t* B = levels_bf + ((size_t)(b * 256 + tn * 128) * 6 + l) * 512;
  const float* inv = invn + (size_t)bl * 256;
  ushort_t* out = simattn + ((size_t)bl * 256 + tm * 128) * 256 + (size_t)tn * 128;
  gemm_tile(A, 3072, B, 3072, 512, [&](int lr, int lc, float v) {
    int i = tm * 128 + lr, j = tn * 128 + lc;
    float s = (i == j) ? -0.0005f : v * inv[j] * 0.044194173824159216f;
    out[(size_t)lr * 256 + lc] = f2bf(s);
  });
}

// ---------------- softmax over 256-wide rows of simattn, in place (bf16) ----------------
__global__ __launch_bounds__(256) void softmax_kernel(ushort_t* simattn) {
  int row = blockIdx.x, t = threadIdx.x;
  __shared__ float red[256];
  float x = bf2f(simattn[(size_t)row * 256 + t]);
  red[t] = x;
  __syncthreads();
  for (int s = 128; s > 0; s >>= 1) { if (t < s) red[t] = fmaxf(red[t], red[t + s]); __syncthreads(); }
  float mx = red[0];
  __syncthreads();
  float e = __expf(x - mx);
  red[t] = e;
  __syncthreads();
  for (int s = 128; s > 0; s >>= 1) { if (t < s) red[t] += red[t + s]; __syncthreads(); }
  float den = red[0];
  simattn[(size_t)row * 256 + t] = f2bf(e / den);
}

// ---------------- PV: levels += attn * levels_snapshot (in place, f32) ----------------
__global__ __launch_bounds__(256) void pv_kernel(const ushort_t* attn, const ushort_t* levelsT,
                                                 float* levels) {
  int bl = blockIdx.z; int tm = blockIdx.x, tn = blockIdx.y;
  int b = bl / 6, l = bl % 6;
  const ushort_t* A = attn + (size_t)bl * 256 * 256 + (size_t)tm * 128 * 256;
  const ushort_t* B = levelsT + ((size_t)bl * 512 + (size_t)tn * 128) * 256;
  gemm_tile(A, 256, B, 256, 256, [&](int lr, int lc, float v) {
    int n = tm * 128 + lr;
    int d = tn * 128 + lc;
    size_t idx = (((size_t)b * 256 + n) * 6 + l) * 512 + d;
    levels[idx] += v;
  });
}

// ---- prep (+fused contrib scale): levels -> scaled levels, levels_bf, levels_pos, inv-norms ----
__global__ __launch_bounds__(128) void prep_kernel(float* levels, const float* pos_emb,
                                                   ushort_t* levels_bf, ushort_t* levels_pos,
                                                   float* invn, int apply) {
  int bid = blockIdx.x;           // (b*256+n)*6 + l
  int l = bid % 6;
  int bn = bid / 6;
  int n = bn & 255, b = bn >> 8;
  int t = threadIdx.x;
  float4 lv = *(const float4*)&levels[(size_t)bid * 512 + t * 4];
  if (apply) {
    float rc = (l == 5) ? (1.0f / 3.0f) : 0.25f;
    lv.x *= rc; lv.y *= rc; lv.z *= rc; lv.w *= rc;
    *(float4*)&levels[(size_t)bid * 512 + t * 4] = lv;   // write back scaled state
  }
  float ss = lv.x * lv.x + lv.y * lv.y + lv.z * lv.z + lv.w * lv.w;
#pragma unroll
  for (int off = 32; off > 0; off >>= 1) ss += __shfl_down(ss, off);
  __shared__ float s2[2];
  if ((t & 63) == 0) s2[t >> 6] = ss;
  __syncthreads();
  if (t == 0) {
    float tot = s2[0] + s2[1];
    invn[(size_t)(b * 6 + l) * 256 + n] = 1.0f / fmaxf(sqrtf(tot), 1e-12f);
  }
  ushort4 o;
  o.x = f2bf(lv.x); o.y = f2bf(lv.y); o.z = f2bf(lv.z); o.w = f2bf(lv.w);
  *(ushort4*)&levels_bf[(size_t)bid * 512 + t * 4] = o;
  if (l >= 1) {
    float4 pu = *(const float4*)&pos_emb[(size_t)n * 512 + t * 4];
    ushort4 op;
    op.x = f2bf(lv.x + pu.x);
    op.y = f2bf(lv.y + pu.y);
    op.z = f2bf(lv.z + pu.z);
    op.w = f2bf(lv.w + pu.w);
    *(ushort4*)&levels_pos[((size_t)bn * 5 + (l - 1)) * 512 + t * 4] = op;
  }
}

// ---------------- transpose: levels f32 (b,n,l,d) -> levelsT bf16 (b,l,d,n) ----------------
__global__ __launch_bounds__(256) void transpose_kernel(const float* levels, ushort_t* levelsT) {
  int bl = blockIdx.z; int b = bl / 6, l = bl % 6;
  int n0 = blockIdx.y * 64, d0 = blockIdx.x * 64;
  __shared__ ushort_t tile[64][72];
  int t = threadIdx.x;
#pragma unroll
  for (int rr = 0; rr < 2; ++rr) {
    int c = t + rr * 256;
    int r = c >> 3, c8 = (c & 7) * 8;
    const float* src = &levels[(((size_t)(b * 256 + n0 + r)) * 6 + l) * 512 + d0 + c8];
    float4 v0 = *(const float4*)src;
    float4 v1 = *(const float4*)(src + 4);
    tile[r][c8 + 0] = f2bf(v0.x); tile[r][c8 + 1] = f2bf(v0.y);
    tile[r][c8 + 2] = f2bf(v0.z); tile[r][c8 + 3] = f2bf(v0.w);
    tile[r][c8 + 4] = f2bf(v1.x); tile[r][c8 + 5] = f2bf(v1.y);
    tile[r][c8 + 6] = f2bf(v1.z); tile[r][c8 + 7] = f2bf(v1.w);
  }
  __syncthreads();
#pragma unroll
  for (int rr = 0; rr < 2; ++rr) {
    int c = t + rr * 256;
    int dr = c >> 3, n8 = (c & 7) * 8;
    ushort4 o0, o1;
    o0.x = tile[n8 + 0][dr]; o0.y = tile[n8 + 1][dr]; o0.z = tile[n8 + 2][dr]; o0.w = tile[n8 + 3][dr];
    o1.x = tile[n8 + 4][dr]; o1.y = tile[n8 + 5][dr]; o1.z = tile[n8 + 6][dr]; o1.w = tile[n8 + 7][dr];
    ushort_t* dst = &levelsT[((size_t)bl * 512 + d0 + dr) * 256 + n0 + n8];
    *(ushort4*)dst = o0;
    *(ushort4*)(dst + 4) = o1;
  }
}

// ---------------- patch embed: img(f32) -> tokens bf16 (4096 x 512) ----------------
__global__ __launch_bounds__(256) void tokens_kernel(const float* img, const float* ttw,
                                                     const float* ttb, ushort_t* tokens) {
  int token = blockIdx.x;
  int b = token >> 8, n = token & 255;
  int ph = n >> 4, pw = n & 15;
  __shared__ float patch[196];
  int t = threadIdx.x;
  if (t < 196) {
    int r = t / 14, cc = t % 14;
    patch[t] = img[(size_t)b * 50176 + (size_t)(ph * 14 + r) * 224 + pw * 14 + cc];
  }
  __syncthreads();
  float a0 = ttb[t];
  float a1 = ttb[t + 256];
  for (int k = 0; k < 196; ++k) {
    float p = patch[k];
    a0 += p * ttw[(size_t)k * 512 + t];
    a1 += p * ttw[(size_t)k * 512 + t + 256];
  }
  tokens[(size_t)token * 512 + t]       = f2bf(a0);
  tokens[(size_t)token * 512 + t + 256] = f2bf(a1);
}

// ---------------- init: broadcast init_levels(f32) -> levels f32 (d_out) ----------------
__global__ void init_kernel(const float* init_levels, float* levels) {
  size_t i4 = (size_t)blockIdx.x * 256 + threadIdx.x;
  size_t e0 = i4 * 4;
  int idx = (int)(e0 % 3072);
  *(float4*)&levels[e0] = *(const float4*)&init_levels[idx];
}

// ---------------- scale: levels *= 1/contrib[l], in place (final iteration only) ----------------
__global__ void scale_kernel(float* levels) {
  size_t i4 = (size_t)blockIdx.x * 256 + threadIdx.x;
  size_t e0 = i4 * 4;
  int l = (int)((e0 >> 9) % 6);
  float rc = (l == 5) ? (1.0f / 3.0f) : 0.25f;
  float4 a = *(const float4*)&levels[e0];
  float4 o = {a.x * rc, a.y * rc, a.z * rc, a.w * rc};
  *(float4*)&levels[e0] = o;
}

// ---------------- cvt: f32 -> bf16, 4 elems/thread ----------------
__global__ void cvt_kernel(const float* src, ushort_t* dst, int n4) {
  int i = blockIdx.x * 256 + threadIdx.x;
  if (i >= n4) return;
  float4 v = ((const float4*)src)[i];
  ushort4 o;
  o.x = f2bf(v.x); o.y = f2bf(v.y); o.z = f2bf(v.z); o.w = f2bf(v.w);
  ((ushort4*)dst)[i] = o;
}

extern "C" void kernel_launch(void* const* d_in, const int* in_sizes, int n_in,
                              void* d_out, int out_size, void* d_ws, size_t ws_size,
                              hipStream_t stream) {
  const float* img    = (const float*)d_in[0];
  const float* ttw    = (const float*)d_in[1];
  const float* ttb    = (const float*)d_in[2];
  const float* pos    = (const float*)d_in[3];
  const float* initlv = (const float*)d_in[4];
  const float* bu_w1  = (const float*)d_in[5];
  const float* bu_b1  = (const float*)d_in[6];
  const float* bu_w2  = (const float*)d_in[7];
  const float* bu_b2  = (const float*)d_in[8];
  const float* td_w1  = (const float*)d_in[9];
  const float* td_b1  = (const float*)d_in[10];
  const float* td_w2  = (const float*)d_in[11];
  const float* td_b2  = (const float*)d_in[12];

  float* levels = (float*)d_out;   // (b,n,6,512) f32 state lives in d_out

  const size_t HB = 16777216ull;   // bytes per h group (4096x2048 bf16)

  char* p = (char*)d_ws;
  auto alloc = [&](size_t bytes) { char* r = p; p += (bytes + 255) & ~(size_t)255; return r; };
  float*    invn       = (float*)alloc(24576ull * 4);
  ushort_t* tokens     = (ushort_t*)alloc(2097152ull * 2);
  ushort_t* levels_bf  = (ushort_t*)alloc(12582912ull * 2);
  ushort_t* levels_pos = (ushort_t*)alloc(10485760ull * 2);
  ushort_t* levelsT    = (ushort_t*)alloc(12582912ull * 2);
  ushort_t* simattn    = (ushort_t*)alloc(6291456ull * 2);
  ushort_t* w1_bf      = (ushort_t*)alloc(11534336ull * 2);
  ushort_t* w2_bf      = (ushort_t*)alloc(11534336ull * 2);
  size_t used = (size_t)(p - (char*)d_ws);
  if (used + HB > ws_size) return;                 // can't fit even 1-group h
  int gpp = (int)((ws_size - used) / HB);          // groups per FF pass
  if (gpp > 6) gpp = 6;                            // <=6 contiguous: no g/g+6 race
  ushort_t* h = (ushort_t*)alloc((size_t)gpp * HB);

  cvt_kernel<<<6144, 256, 0, stream>>>(bu_w1, w1_bf, 1572864);
  cvt_kernel<<<5120, 256, 0, stream>>>(td_w1, w1_bf + 6291456ull, 1310720);
  cvt_kernel<<<6144, 256, 0, stream>>>(bu_w2, w2_bf, 1572864);
  cvt_kernel<<<5120, 256, 0, stream>>>(td_w2, w2_bf + 6291456ull, 1310720);
  tokens_kernel<<<4096, 256, 0, stream>>>(img, ttw, ttb, tokens);
  init_kernel<<<12288, 256, 0, stream>>>(initlv, levels);

  for (int it = 0; it < 12; ++it) {
    // scale of the previous iteration's accumulation is fused into prep (apply=1)
    prep_kernel<<<24576, 128, 0, stream>>>(levels, pos, levels_bf, levels_pos, invn,
                                           it > 0 ? 1 : 0);
    transpose_kernel<<<dim3(8, 4, 96), 256, 0, stream>>>(levels, levelsT);
    sim_kernel<<<dim3(2, 2, 96), 256, 0, stream>>>(levels_bf, invn, simattn);
    softmax_kernel<<<24576, 256, 0, stream>>>(simattn);
    pv_kernel<<<dim3(2, 4, 96), 256, 0, stream>>>(simattn, levelsT, levels);
    for (int g0 = 0; g0 < 11; g0 += gpp) {
      int gn = 11 - g0 < gpp ? 11 - g0 : gpp;
      ff1_kernel<<<dim3(32, 8, gn), 256, 0, stream>>>(g0, tokens, levels_bf, levels_pos,
                                                      w1_bf, bu_b1, td_b1, h);
      ff2_kernel<<<dim3(16, 2, gn), 512, 0, stream>>>(g0, h, w2_bf, bu_b2, td_b2, levels);
    }
  }
  scale_kernel<<<12288, 256, 0, stream>>>(levels);   // final contrib division
}

// Round 9
// 5594.802 us; speedup vs baseline: 1.4829x; 1.2385x over previous
//
#include <hip/hip_runtime.h>
#include <hip/hip_bf16.h>
#include <math.h>

typedef unsigned short ushort_t;

#define DEV __device__ __forceinline__

DEV float bf2f(ushort_t u) {
  return __uint_as_float(((unsigned int)u) << 16);
}
DEV ushort_t f2bf(float f) {
  unsigned int x = __float_as_uint(f);
  return (ushort_t)((x + 0x7FFFu + ((x >> 16) & 1u)) >> 16);
}

// Fast exact-gelu: Abramowitz-Stegun 7.1.26 erf approx, |err| <= 1.5e-7.
DEV float gelu_f(float x) {
  float z = fabsf(x) * 0.70710678118654752f;
  float t = __builtin_amdgcn_rcpf(1.0f + 0.3275911f * z);
  float p = t * (0.254829592f +
            t * (-0.284496736f +
            t * (1.421413741f +
            t * (-1.453152027f +
            t * 1.061405429f))));
  float e = 1.0f - p * __expf(-z * z);      // erf(|x|/sqrt(2))
  float s = (x >= 0.f) ? e : -e;
  return 0.5f * x * (1.0f + s);
}

using bf16x8 = __attribute__((ext_vector_type(8))) __bf16;
using f32x4  = __attribute__((ext_vector_type(4))) float;

DEV void gload16(const ushort_t* g, ushort_t* l) {
  __builtin_amdgcn_global_load_lds((const __attribute__((address_space(1))) void*)g,
                                   (__attribute__((address_space(3))) void*)l, 16, 0, 0);
}

// Stage a 128x64 bf16 tile into LDS, 256 threads, SOURCE-side XOR swizzle:
// LDS chunk (row, cslot) holds global slot cslot^(row&7). Read with the same XOR.
DEV void stage_sw(const ushort_t* g, int ld, ushort_t* lds, int t) {
  int w = t >> 6;
#pragma unroll
  for (int r = 0; r < 4; ++r) {
    int chunk = r * 256 + t;
    int row = chunk >> 3;
    int sw  = ((chunk & 7) ^ (row & 7)) * 8;
    const ushort_t* gp = g + (size_t)row * ld + sw;
    ushort_t* lp = lds + (size_t)(r * 256 + w * 64) * 8;   // linear dest (HW adds lane*16B)
    gload16(gp, lp);
  }
}

// ============================================================================
// 128x128 pipelined 2-phase GEMM (T3 minimal: issue-early + counted vmcnt(8),
// T2 both-sides swizzle). 256 threads = 4 waves (2x2), 4x4 16x16x32 frags.
// C = A (MxK,row-major,lda) * B^T, B (NxK,row-major,ldb). K % 64 == 0, K>=128.
// Used by ff1 / sim / pv.
// ============================================================================
template <typename F>
DEV void gemm_tile(const ushort_t* A, int lda, const ushort_t* B, int ldb, int K, F&& epi) {
  __shared__ alignas(16) ushort_t As[2][128 * 64];
  __shared__ alignas(16) ushort_t Bs[2][128 * 64];
  int t = threadIdx.x;
  int lane = t & 63;
  int w = t >> 6;
  int wr = w >> 1, wc = w & 1;
  const int nk = K >> 6;
  f32x4 acc[4][4];
#pragma unroll
  for (int m = 0; m < 4; ++m)
#pragma unroll
    for (int n = 0; n < 4; ++n) acc[m][n] = (f32x4){0.f, 0.f, 0.f, 0.f};

  // swizzled read offsets: row&7 == lane&7 for all fragment rows
  int aoff[4][2], boff[4][2];
#pragma unroll
  for (int m = 0; m < 4; ++m)
#pragma unroll
    for (int kk = 0; kk < 2; ++kk) {
      int ks = kk * 4 + (lane >> 4);
      aoff[m][kk] = (wr * 64 + m * 16 + (lane & 15)) * 64 + ((ks ^ (lane & 7)) * 8);
      boff[m][kk] = (wc * 64 + m * 16 + (lane & 15)) * 64 + ((ks ^ (lane & 7)) * 8);
    }

  // prologue: stage tile 0
  stage_sw(A, lda, As[0], t);
  stage_sw(B, ldb, Bs[0], t);

  for (int kt = 0; kt < nk; ++kt) {
    int cur = kt & 1;
    int nxt = (kt + 1 < nk) ? kt + 1 : kt;         // clamped tail keeps vmcnt uniform
    // issue next tile's loads BEFORE waiting on current (they fly during compute)
    stage_sw(A + (size_t)nxt * 64, lda, As[cur ^ 1], t);
    stage_sw(B + (size_t)nxt * 64, ldb, Bs[cur ^ 1], t);
    asm volatile("s_waitcnt vmcnt(8)" ::: "memory");   // tile-kt loads landed (8 newer in flight)
    __builtin_amdgcn_s_barrier();                      // all waves' tile-kt data visible
    __builtin_amdgcn_sched_barrier(0);                 // no ds_read hoisting above this point
    const ushort_t* asb = &As[cur][0];
    const ushort_t* bsb = &Bs[cur][0];
#pragma unroll
    for (int kk = 0; kk < 2; ++kk) {
      bf16x8 af[4], bfr[4];
#pragma unroll
      for (int m = 0; m < 4; ++m) af[m] = *(const bf16x8*)&asb[aoff[m][kk]];
#pragma unroll
      for (int n = 0; n < 4; ++n) bfr[n] = *(const bf16x8*)&bsb[boff[n][kk]];
      __builtin_amdgcn_s_setprio(1);
#pragma unroll
      for (int m = 0; m < 4; ++m)
#pragma unroll
        for (int n = 0; n < 4; ++n)
          acc[m][n] = __builtin_amdgcn_mfma_f32_16x16x32_bf16(af[m], bfr[n], acc[m][n], 0, 0, 0);
      __builtin_amdgcn_s_setprio(0);
    }
    __builtin_amdgcn_s_barrier();                      // compute(kt) done before buf reuse
  }

#pragma unroll
  for (int m = 0; m < 4; ++m)
#pragma unroll
    for (int n = 0; n < 4; ++n)
#pragma unroll
      for (int r = 0; r < 4; ++r) {
        int lr = wr * 64 + m * 16 + (lane >> 4) * 4 + r;
        int lc = wc * 64 + n * 16 + (lane & 15);
        epi(lr, lc, acc[m][n][r]);
      }
}

// ============================================================================
// 256x256 8-phase GEMM (T2 swizzle + T3/T4 counted vmcnt + T5 setprio).
// Used for ff2 (K=2048, nk=32). C = A (MxK,row-major) * B^T, B (NxK,row-major).
// ============================================================================
#define MFMA_QUAD(QM, QN)                                                      \
  _Pragma("unroll") for (int m_ = 0; m_ < 4; ++m_)                             \
  _Pragma("unroll") for (int n_ = 0; n_ < 2; ++n_)                             \
  _Pragma("unroll") for (int kk_ = 0; kk_ < 2; ++kk_)                          \
    acc[QM][QN][m_][n_] = __builtin_amdgcn_mfma_f32_16x16x32_bf16(             \
        aF[m_][kk_], bF[QN][n_][kk_], acc[QM][QN][m_][n_], 0, 0, 0);

template <typename F>
DEV void gemm256(const ushort_t* A, int lda, const ushort_t* B, int ldb, int K, F&& epi) {
  __shared__ alignas(16) ushort_t As[2][256 * 64];
  __shared__ alignas(16) ushort_t Bs[2][256 * 64];
  const int tid = threadIdx.x;
  const int lane = tid & 63;
  const int w = tid >> 6;
  const int ur = w >> 2, uc = w & 3;
  const int nk = K >> 6;

  const int c0 = tid, c1 = 512 + tid;
  const int row0 = c0 >> 3, row1 = c1 >> 3;
  const int sw0 = ((c0 & 7) ^ (row0 & 7)) * 8;
  const int sw1 = ((c1 & 7) ^ (row1 & 7)) * 8;
  const ushort_t* Ab0 = A + (size_t)row0 * lda + sw0;
  const ushort_t* Ab1 = A + (size_t)row1 * lda + sw1;
  const ushort_t* Bb0 = B + (size_t)row0 * ldb + sw0;
  const ushort_t* Bb1 = B + (size_t)row1 * ldb + sw1;
  const int ld0 = (0 * 512 + w * 64) * 8;
  const int ld1 = (1 * 512 + w * 64) * 8;

  auto stageA = [&](int t, int hh, int b) {
    const ushort_t* g0 = Ab0 + (size_t)hh * 128 * lda + t * 64;
    const ushort_t* g1 = Ab1 + (size_t)hh * 128 * lda + t * 64;
    ushort_t* l = &As[b][hh * 8192];
    gload16(g0, l + ld0);
    gload16(g1, l + ld1);
  };
  auto stageB = [&](int t, int hh, int b) {
    const ushort_t* g0 = Bb0 + (size_t)hh * 128 * ldb + t * 64;
    const ushort_t* g1 = Bb1 + (size_t)hh * 128 * ldb + t * 64;
    ushort_t* l = &Bs[b][hh * 8192];
    gload16(g0, l + ld0);
    gload16(g1, l + ld1);
  };

  int aoff[4][2], boff[2][2];
#pragma unroll
  for (int m = 0; m < 4; ++m)
#pragma unroll
    for (int kk = 0; kk < 2; ++kk) {
      int row = ur * 64 + m * 16 + (lane & 15);
      int ks = kk * 4 + (lane >> 4);
      aoff[m][kk] = row * 64 + ((ks ^ (lane & 7)) * 8);
    }
#pragma unroll
  for (int n = 0; n < 2; ++n)
#pragma unroll
    for (int kk = 0; kk < 2; ++kk) {
      int row = uc * 32 + n * 16 + (lane & 15);
      int ks = kk * 4 + (lane >> 4);
      boff[n][kk] = row * 64 + ((ks ^ (lane & 7)) * 8);
    }

  f32x4 acc[2][2][4][2];
#pragma unroll
  for (int qm = 0; qm < 2; ++qm)
#pragma unroll
    for (int qn = 0; qn < 2; ++qn)
#pragma unroll
      for (int m = 0; m < 4; ++m)
#pragma unroll
        for (int n = 0; n < 2; ++n) acc[qm][qn][m][n] = (f32x4){0.f, 0.f, 0.f, 0.f};

  stageA(0, 0, 0);
  stageB(0, 0, 0);
  stageB(0, 1, 0);
  stageA(0, 1, 0);
  stageA(1, 0, 1);
  stageB(1, 0, 1);
  asm volatile("s_waitcnt vmcnt(8)" ::: "memory");
  __builtin_amdgcn_s_barrier();

  bf16x8 aF[4][2], bF[2][2][2];

  for (int t = 0; t < nk; ++t) {
    const int b = t & 1;
    const ushort_t* asb = &As[b][0];
    const ushort_t* bsb = &Bs[b][0];
    const int t1 = (t + 1 < nk) ? t + 1 : nk - 1;
    const int t2 = (t + 2 < nk) ? t + 2 : nk - 1;

    // phase 0: quadrant (0,0); stage B1(t+1)
#pragma unroll
    for (int m = 0; m < 4; ++m)
#pragma unroll
      for (int kk = 0; kk < 2; ++kk) aF[m][kk] = *(const bf16x8*)&asb[aoff[m][kk]];
#pragma unroll
    for (int n = 0; n < 2; ++n)
#pragma unroll
      for (int kk = 0; kk < 2; ++kk) bF[0][n][kk] = *(const bf16x8*)&bsb[boff[n][kk]];
    stageB(t1, 1, (t + 1) & 1);
    __builtin_amdgcn_s_barrier();
    asm volatile("s_waitcnt lgkmcnt(0)" ::: "memory");
    __builtin_amdgcn_s_setprio(1);
    MFMA_QUAD(0, 0)
    __builtin_amdgcn_s_setprio(0);
    asm volatile("s_waitcnt vmcnt(8)" ::: "memory");
    __builtin_amdgcn_s_barrier();

    // phase 1: quadrant (0,1); stage A1(t+1)
#pragma unroll
    for (int n = 0; n < 2; ++n)
#pragma unroll
      for (int kk = 0; kk < 2; ++kk) bF[1][n][kk] = *(const bf16x8*)&bsb[boff[n][kk] + 8192];
    stageA(t1, 1, (t + 1) & 1);
    __builtin_amdgcn_s_barrier();
    asm volatile("s_waitcnt lgkmcnt(0)" ::: "memory");
    __builtin_amdgcn_s_setprio(1);
    MFMA_QUAD(0, 1)
    __builtin_amdgcn_s_setprio(0);
    asm volatile("s_waitcnt vmcnt(8)" ::: "memory");
    __builtin_amdgcn_s_barrier();

    // phase 2: quadrant (1,0); stage A0(t+2)
#pragma unroll
    for (int m = 0; m < 4; ++m)
#pragma unroll
      for (int kk = 0; kk < 2; ++kk) aF[m][kk] = *(const bf16x8*)&asb[aoff[m][kk] + 8192];
    stageA(t2, 0, b);
    __builtin_amdgcn_s_barrier();
    asm volatile("s_waitcnt lgkmcnt(0)" ::: "memory");
    __builtin_amdgcn_s_setprio(1);
    MFMA_QUAD(1, 0)
    __builtin_amdgcn_s_setprio(0);
    __builtin_amdgcn_s_barrier();

    // phase 3: quadrant (1,1); stage B0(t+2)
    stageB(t2, 0, b);
    __builtin_amdgcn_s_barrier();
    __builtin_amdgcn_s_setprio(1);
    MFMA_QUAD(1, 1)
    __builtin_amdgcn_s_setprio(0);
    asm volatile("s_waitcnt vmcnt(8)" ::: "memory");
    __builtin_amdgcn_s_barrier();
  }
  asm volatile("s_waitcnt vmcnt(0)" ::: "memory");

#pragma unroll
  for (int qm = 0; qm < 2; ++qm)
#pragma unroll
    for (int qn = 0; qn < 2; ++qn)
#pragma unroll
      for (int m = 0; m < 4; ++m)
#pragma unroll
        for (int n = 0; n < 2; ++n)
#pragma unroll
          for (int r = 0; r < 4; ++r) {
            int lr = qm * 128 + ur * 64 + m * 16 + (lane >> 4) * 4 + r;
            int lc = qn * 128 + uc * 32 + n * 16 + (lane & 15);
            epi(lr, lc, acc[qm][qn][m][n][r]);
          }
}

// ---------------- FF layer 1: x(512) -> h(2048), 128x128 pipelined, bias+gelu -> bf16 ----------
__global__ __launch_bounds__(256) void ff1_kernel(
    int g0, const ushort_t* tokens, const ushort_t* levels_bf, const ushort_t* levels_pos,
    const ushort_t* w1_bf, const float* bu_b1, const float* td_b1, ushort_t* h) {
  int g = g0 + blockIdx.z;
  int tm = blockIdx.x, tn = blockIdx.y;
  const ushort_t* A; int lda;
  if (g == 0)      { A = tokens     + (size_t)tm * 128 * 512;                              lda = 512;  }
  else if (g < 6)  { A = levels_bf  + (size_t)tm * 128 * 3072 + (size_t)(g - 1) * 512;     lda = 3072; }
  else             { A = levels_pos + (size_t)tm * 128 * 2560 + (size_t)(g - 6) * 512;     lda = 2560; }
  const ushort_t* W = w1_bf + (size_t)g * 2048 * 512 + (size_t)tn * 128 * 512;
  const float* bias = (g < 6) ? (bu_b1 + (size_t)g * 2048) : (td_b1 + (size_t)(g - 6) * 2048);
  ushort_t* out = h + ((size_t)(g - g0) * 4096 + (size_t)tm * 128) * 2048 + (size_t)tn * 128;
  gemm_tile(A, lda, W, 512, 512, [&](int lr, int lc, float v) {
    float x = v + bias[tn * 128 + lc];
    out[(size_t)lr * 2048 + lc] = f2bf(gelu_f(x));
  });
}

// ---------------- FF layer 2: h(2048) -> 512, 8-phase, fused bias, accumulate into levels -------
// RACE GUARD: one ff2 launch must never contain both group g and g+6 (both
// accumulate the SAME level l). Contiguous ranges of length <= 6 are safe.
__global__ __launch_bounds__(512, 2) void ff2_kernel(
    int g0, const ushort_t* h, const ushort_t* w2_bf, const float* bu_b2, const float* td_b2,
    float* levels) {
  int g = g0 + blockIdx.z;
  int tm = blockIdx.x, tn = blockIdx.y;
  const ushort_t* A = h + ((size_t)(g - g0) * 4096 + (size_t)tm * 256) * 2048;
  const ushort_t* W = w2_bf + (size_t)g * 512 * 2048 + (size_t)tn * 256 * 2048;
  int l = (g < 6) ? g : (g - 6);
  const float* bias = (g < 6) ? (bu_b2 + (size_t)g * 512) : (td_b2 + (size_t)(g - 6) * 512);
  gemm256(A, 2048, W, 2048, 2048, [&](int lr, int lc, float v) {
    int bn = tm * 256 + lr;
    int d  = tn * 256 + lc;
    size_t idx = ((size_t)bn * 6 + l) * 512 + d;
    levels[idx] += v + bias[d];
  });
}

// ---------------- SIM: Gram(levels) with fused inv-norm column scale + diag mask -> bf16 --------
__global__ __launch_bounds__(256) void sim_kernel(const ushort_t* levels_bf, const float* invn,
                                                  ushort_t* simattn) {
  int bl = blockIdx.z; int tm = blockIdx.x, tn = blockIdx.y;
  int b = bl / 6, l = bl % 6;
  const ushort_t* A = levels_bf + ((size_t)(b * 256 + tm * 128) * 6 + l) * 512;
  const ushort_t* B = levels_bf + ((size_t)(b * 256 + tn * 128) * 6 + l) * 512;
  const float* inv = invn + (size_t)bl * 256;
  ushort_t* out = simattn + ((size_t)bl * 256 + tm * 128) * 256 + (size_t)tn * 128;
  gemm_tile(A, 3072, B, 3072, 512, [&](int lr, int lc, float v) {
    int i = tm * 128 + lr, j = tn * 128 + lc;
    float s = (i == j) ? -0.0005f : v * inv[j] * 0.044194173824159216f;
    out[(size_t)lr * 256 + lc] = f2bf(s);
  });
}

// ---------------- softmax over 256-wide rows of simattn, in place (bf16) ----------------
__global__ __launch_bounds__(256) void softmax_kernel(ushort_t* simattn) {
  int row = blockIdx.x, t = threadIdx.x;
  __shared__ float red[256];
  float x = bf2f(simattn[(size_t)row * 256 + t]);
  red[t] = x;
  __syncthreads();
  for (int s = 128; s > 0; s >>= 1) { if (t < s) red[t] = fmaxf(red[t], red[t + s]); __syncthreads(); }
  float mx = red[0];
  __syncthreads();
  float e = __expf(x - mx);
  red[t] = e;
  __syncthreads();
  for (int s = 128; s > 0; s >>= 1) { if (t < s) red[t] += red[t + s]; __syncthreads(); }
  float den = red[0];
  simattn[(size_t)row * 256 + t] = f2bf(e / den);
}

// ---------------- PV: levels += attn * levels_snapshot (in place, f32) ----------------
__global__ __launch_bounds__(256) void pv_kernel(const ushort_t* attn, const ushort_t* levelsT,
                                                 float* levels) {
  int bl = blockIdx.z; int tm = blockIdx.x, tn = blockIdx.y;
  int b = bl / 6, l = bl % 6;
  const ushort_t* A = attn + (size_t)bl * 256 * 256 + (size_t)tm * 128 * 256;
  const ushort_t* B = levelsT + ((size_t)bl * 512 + (size_t)tn * 128) * 256;
  gemm_tile(A, 256, B, 256, 256, [&](int lr, int lc, float v) {
    int n = tm * 128 + lr;
    int d = tn * 128 + lc;
    size_t idx = (((size_t)b * 256 + n) * 6 + l) * 512 + d;
    levels[idx] += v;
  });
}

// ---- prep (+fused contrib scale): levels -> scaled levels, levels_bf, levels_pos, inv-norms ----
__global__ __launch_bounds__(128) void prep_kernel(float* levels, const float* pos_emb,
                                                   ushort_t* levels_bf, ushort_t* levels_pos,
                                                   float* invn, int apply) {
  int bid = blockIdx.x;           // (b*256+n)*6 + l
  int l = bid % 6;
  int bn = bid / 6;
  int n = bn & 255, b = bn >> 8;
  int t = threadIdx.x;
  float4 lv = *(const float4*)&levels[(size_t)bid * 512 + t * 4];
  if (apply) {
    float rc = (l == 5) ? (1.0f / 3.0f) : 0.25f;
    lv.x *= rc; lv.y *= rc; lv.z *= rc; lv.w *= rc;
    *(float4*)&levels[(size_t)bid * 512 + t * 4] = lv;   // write back scaled state
  }
  float ss = lv.x * lv.x + lv.y * lv.y + lv.z * lv.z + lv.w * lv.w;
#pragma unroll
  for (int off = 32; off > 0; off >>= 1) ss += __shfl_down(ss, off);
  __shared__ float s2[2];
  if ((t & 63) == 0) s2[t >> 6] = ss;
  __syncthreads();
  if (t == 0) {
    float tot = s2[0] + s2[1];
    invn[(size_t)(b * 6 + l) * 256 + n] = 1.0f / fmaxf(sqrtf(tot), 1e-12f);
  }
  ushort4 o;
  o.x = f2bf(lv.x); o.y = f2bf(lv.y); o.z = f2bf(lv.z); o.w = f2bf(lv.w);
  *(ushort4*)&levels_bf[(size_t)bid * 512 + t * 4] = o;
  if (l >= 1) {
    float4 pu = *(const float4*)&pos_emb[(size_t)n * 512 + t * 4];
    ushort4 op;
    op.x = f2bf(lv.x + pu.x);
    op.y = f2bf(lv.y + pu.y);
    op.z = f2bf(lv.z + pu.z);
    op.w = f2bf(lv.w + pu.w);
    *(ushort4*)&levels_pos[((size_t)bn * 5 + (l - 1)) * 512 + t * 4] = op;
  }
}

// ---------------- transpose: levels f32 (b,n,l,d) -> levelsT bf16 (b,l,d,n) ----------------
__global__ __launch_bounds__(256) void transpose_kernel(const float* levels, ushort_t* levelsT) {
  int bl = blockIdx.z; int b = bl / 6, l = bl % 6;
  int n0 = blockIdx.y * 64, d0 = blockIdx.x * 64;
  __shared__ ushort_t tile[64][72];
  int t = threadIdx.x;
#pragma unroll
  for (int rr = 0; rr < 2; ++rr) {
    int c = t + rr * 256;
    int r = c >> 3, c8 = (c & 7) * 8;
    const float* src = &levels[(((size_t)(b * 256 + n0 + r)) * 6 + l) * 512 + d0 + c8];
    float4 v0 = *(const float4*)src;
    float4 v1 = *(const float4*)(src + 4);
    tile[r][c8 + 0] = f2bf(v0.x); tile[r][c8 + 1] = f2bf(v0.y);
    tile[r][c8 + 2] = f2bf(v0.z); tile[r][c8 + 3] = f2bf(v0.w);
    tile[r][c8 + 4] = f2bf(v1.x); tile[r][c8 + 5] = f2bf(v1.y);
    tile[r][c8 + 6] = f2bf(v1.z); tile[r][c8 + 7] = f2bf(v1.w);
  }
  __syncthreads();
#pragma unroll
  for (int rr = 0; rr < 2; ++rr) {
    int c = t + rr * 256;
    int dr = c >> 3, n8 = (c & 7) * 8;
    ushort4 o0, o1;
    o0.x = tile[n8 + 0][dr]; o0.y = tile[n8 + 1][dr]; o0.z = tile[n8 + 2][dr]; o0.w = tile[n8 + 3][dr];
    o1.x = tile[n8 + 4][dr]; o1.y = tile[n8 + 5][dr]; o1.z = tile[n8 + 6][dr]; o1.w = tile[n8 + 7][dr];
    ushort_t* dst = &levelsT[((size_t)bl * 512 + d0 + dr) * 256 + n0 + n8];
    *(ushort4*)dst = o0;
    *(ushort4*)(dst + 4) = o1;
  }
}

// ---------------- patch embed: img(f32) -> tokens bf16 (4096 x 512) ----------------
__global__ __launch_bounds__(256) void tokens_kernel(const float* img, const float* ttw,
                                                     const float* ttb, ushort_t* tokens) {
  int token = blockIdx.x;
  int b = token >> 8, n = token & 255;
  int ph = n >> 4, pw = n & 15;
  __shared__ float patch[196];
  int t = threadIdx.x;
  if (t < 196) {
    int r = t / 14, cc = t % 14;
    patch[t] = img[(size_t)b * 50176 + (size_t)(ph * 14 + r) * 224 + pw * 14 + cc];
  }
  __syncthreads();
  float a0 = ttb[t];
  float a1 = ttb[t + 256];
  for (int k = 0; k < 196; ++k) {
    float p = patch[k];
    a0 += p * ttw[(size_t)k * 512 + t];
    a1 += p * ttw[(size_t)k * 512 + t + 256];
  }
  tokens[(size_t)token * 512 + t]       = f2bf(a0);
  tokens[(size_t)token * 512 + t + 256] = f2bf(a1);
}

// ---------------- init: broadcast init_levels(f32) -> levels f32 (d_out) ----------------
__global__ void init_kernel(const float* init_levels, float* levels) {
  size_t i4 = (size_t)blockIdx.x * 256 + threadIdx.x;
  size_t e0 = i4 * 4;
  int idx = (int)(e0 % 3072);
  *(float4*)&levels[e0] = *(const float4*)&init_levels[idx];
}

// ---------------- scale: levels *= 1/contrib[l], in place (final iteration only) ----------------
__global__ void scale_kernel(float* levels) {
  size_t i4 = (size_t)blockIdx.x * 256 + threadIdx.x;
  size_t e0 = i4 * 4;
  int l = (int)((e0 >> 9) % 6);
  float rc = (l == 5) ? (1.0f / 3.0f) : 0.25f;
  float4 a = *(const float4*)&levels[e0];
  float4 o = {a.x * rc, a.y * rc, a.z * rc, a.w * rc};
  *(float4*)&levels[e0] = o;
}

// ---------------- cvt: f32 -> bf16, 4 elems/thread ----------------
__global__ void cvt_kernel(const float* src, ushort_t* dst, int n4) {
  int i = blockIdx.x * 256 + threadIdx.x;
  if (i >= n4) return;
  float4 v = ((const float4*)src)[i];
  ushort4 o;
  o.x = f2bf(v.x); o.y = f2bf(v.y); o.z = f2bf(v.z); o.w = f2bf(v.w);
  ((ushort4*)dst)[i] = o;
}

extern "C" void kernel_launch(void* const* d_in, const int* in_sizes, int n_in,
                              void* d_out, int out_size, void* d_ws, size_t ws_size,
                              hipStream_t stream) {
  const float* img    = (const float*)d_in[0];
  const float* ttw    = (const float*)d_in[1];
  const float* ttb    = (const float*)d_in[2];
  const float* pos    = (const float*)d_in[3];
  const float* initlv = (const float*)d_in[4];
  const float* bu_w1  = (const float*)d_in[5];
  const float* bu_b1  = (const float*)d_in[6];
  const float* bu_w2  = (const float*)d_in[7];
  const float* bu_b2  = (const float*)d_in[8];
  const float* td_w1  = (const float*)d_in[9];
  const float* td_b1  = (const float*)d_in[10];
  const float* td_w2  = (const float*)d_in[11];
  const float* td_b2  = (const float*)d_in[12];

  float* levels = (float*)d_out;   // (b,n,6,512) f32 state lives in d_out

  const size_t HB = 16777216ull;   // bytes per h group (4096x2048 bf16)

  char* p = (char*)d_ws;
  auto alloc = [&](size_t bytes) { char* r = p; p += (bytes + 255) & ~(size_t)255; return r; };
  float*    invn       = (float*)alloc(24576ull * 4);
  ushort_t* tokens     = (ushort_t*)alloc(2097152ull * 2);
  ushort_t* levels_bf  = (ushort_t*)alloc(12582912ull * 2);
  ushort_t* levels_pos = (ushort_t*)alloc(10485760ull * 2);
  ushort_t* levelsT    = (ushort_t*)alloc(12582912ull * 2);
  ushort_t* simattn    = (ushort_t*)alloc(6291456ull * 2);
  ushort_t* w1_bf      = (ushort_t*)alloc(11534336ull * 2);
  ushort_t* w2_bf      = (ushort_t*)alloc(11534336ull * 2);
  size_t used = (size_t)(p - (char*)d_ws);
  if (used + HB > ws_size) return;                 // can't fit even 1-group h
  int gpp = (int)((ws_size - used) / HB);          // groups per FF pass
  if (gpp > 6) gpp = 6;                            // <=6 contiguous: no g/g+6 race
  ushort_t* h = (ushort_t*)alloc((size_t)gpp * HB);

  cvt_kernel<<<6144, 256, 0, stream>>>(bu_w1, w1_bf, 1572864);
  cvt_kernel<<<5120, 256, 0, stream>>>(td_w1, w1_bf + 6291456ull, 1310720);
  cvt_kernel<<<6144, 256, 0, stream>>>(bu_w2, w2_bf, 1572864);
  cvt_kernel<<<5120, 256, 0, stream>>>(td_w2, w2_bf + 6291456ull, 1310720);
  tokens_kernel<<<4096, 256, 0, stream>>>(img, ttw, ttb, tokens);
  init_kernel<<<12288, 256, 0, stream>>>(initlv, levels);

  for (int it = 0; it < 12; ++it) {
    // scale of the previous iteration's accumulation is fused into prep (apply=1)
    prep_kernel<<<24576, 128, 0, stream>>>(levels, pos, levels_bf, levels_pos, invn,
                                           it > 0 ? 1 : 0);
    transpose_kernel<<<dim3(8, 4, 96), 256, 0, stream>>>(levels, levelsT);
    sim_kernel<<<dim3(2, 2, 96), 256, 0, stream>>>(levels_bf, invn, simattn);
    softmax_kernel<<<24576, 256, 0, stream>>>(simattn);
    pv_kernel<<<dim3(2, 4, 96), 256, 0, stream>>>(simattn, levelsT, levels);
    for (int g0 = 0; g0 < 11; g0 += gpp) {
      int gn = 11 - g0 < gpp ? 11 - g0 : gpp;
      ff1_kernel<<<dim3(32, 16, gn), 256, 0, stream>>>(g0, tokens, levels_bf, levels_pos,
                                                       w1_bf, bu_b1, td_b1, h);
      ff2_kernel<<<dim3(16, 2, gn), 512, 0, stream>>>(g0, h, w2_bf, bu_b2, td_b2, levels);
    }
  }
  scale_kernel<<<12288, 256, 0, stream>>>(levels);   // final contrib division
}

// Round 10
// 5382.502 us; speedup vs baseline: 1.5414x; 1.0394x over previous
//
#include <hip/hip_runtime.h>
#include <hip/hip_bf16.h>
#include <math.h>

typedef unsigned short ushort_t;

#define DEV __device__ __forceinline__

DEV float bf2f(ushort_t u) {
  return __uint_as_float(((unsigned int)u) << 16);
}
DEV ushort_t f2bf(float f) {
  unsigned int x = __float_as_uint(f);
  return (ushort_t)((x + 0x7FFFu + ((x >> 16) & 1u)) >> 16);
}

// Fast exact-gelu: Abramowitz-Stegun 7.1.26 erf approx, |err| <= 1.5e-7.
DEV float gelu_f(float x) {
  float z = fabsf(x) * 0.70710678118654752f;
  float t = __builtin_amdgcn_rcpf(1.0f + 0.3275911f * z);
  float p = t * (0.254829592f +
            t * (-0.284496736f +
            t * (1.421413741f +
            t * (-1.453152027f +
            t * 1.061405429f))));
  float e = 1.0f - p * __expf(-z * z);      // erf(|x|/sqrt(2))
  float s = (x >= 0.f) ? e : -e;
  return 0.5f * x * (1.0f + s);
}

using bf16x8 = __attribute__((ext_vector_type(8))) __bf16;
using f32x4  = __attribute__((ext_vector_type(4))) float;

DEV void gload16(const ushort_t* g, ushort_t* l) {
  __builtin_amdgcn_global_load_lds((const __attribute__((address_space(1))) void*)g,
                                   (__attribute__((address_space(3))) void*)l, 16, 0, 0);
}

// ---- linear staging (R4): 128x64 bf16 tile, 256 threads ----
DEV void stage_tile(const ushort_t* g, int ld, ushort_t* lds, int t) {
  int w = t >> 6;
#pragma unroll
  for (int r = 0; r < 4; ++r) {
    int chunk = r * 256 + t;
    const ushort_t* gp = g + (size_t)(chunk >> 3) * ld + (size_t)(chunk & 7) * 8;
    ushort_t* lp = lds + (size_t)(r * 256 + w * 64) * 8;
    gload16(gp, lp);
  }
}

// ---- swizzled staging: LDS chunk (row,cslot) holds global slot cslot^(row&7) ----
DEV void stage_sw(const ushort_t* g, int ld, ushort_t* lds, int t) {
  int w = t >> 6;
#pragma unroll
  for (int r = 0; r < 4; ++r) {
    int chunk = r * 256 + t;
    int row = chunk >> 3;
    int sw  = ((chunk & 7) ^ (row & 7)) * 8;
    const ushort_t* gp = g + (size_t)row * ld + sw;
    ushort_t* lp = lds + (size_t)(r * 256 + w * 64) * 8;
    gload16(gp, lp);
  }
}

// ============================================================================
// PLAIN 128x128 2-phase GEMM (R4-proven; 32KB LDS -> ~3 blocks/CU). Best for
// ff1 whose fat epilogue needs co-resident blocks. 256 thr = 4 waves (2x2).
// ============================================================================
template <typename F>
DEV void gemm_tileP(const ushort_t* A, int lda, const ushort_t* B, int ldb, int K, F&& epi) {
  __shared__ alignas(16) ushort_t As[128 * 64];
  __shared__ alignas(16) ushort_t Bs[128 * 64];
  int t = threadIdx.x;
  int lane = t & 63;
  int w = t >> 6;
  int wr = w >> 1, wc = w & 1;
  f32x4 acc[4][4];
#pragma unroll
  for (int m = 0; m < 4; ++m)
#pragma unroll
    for (int n = 0; n < 4; ++n) acc[m][n] = (f32x4){0.f, 0.f, 0.f, 0.f};

  for (int kt = 0; kt < K; kt += 64) {
    __syncthreads();
    stage_tile(A + kt, lda, As, t);
    stage_tile(B + kt, ldb, Bs, t);
    __syncthreads();
#pragma unroll
    for (int kk = 0; kk < 2; ++kk) {
      int kb = kk * 32 + (lane >> 4) * 8;
      bf16x8 af[4], bfr[4];
#pragma unroll
      for (int m = 0; m < 4; ++m)
        af[m] = *(const bf16x8*)&As[(size_t)(wr * 64 + m * 16 + (lane & 15)) * 64 + kb];
#pragma unroll
      for (int n = 0; n < 4; ++n)
        bfr[n] = *(const bf16x8*)&Bs[(size_t)(wc * 64 + n * 16 + (lane & 15)) * 64 + kb];
#pragma unroll
      for (int m = 0; m < 4; ++m)
#pragma unroll
        for (int n = 0; n < 4; ++n)
          acc[m][n] = __builtin_amdgcn_mfma_f32_16x16x32_bf16(af[m], bfr[n], acc[m][n], 0, 0, 0);
    }
  }
  epi(wr, wc, lane, acc);
}

// ============================================================================
// PIPELINED 128x128 GEMM (R9: issue-early + vmcnt(8) + swizzle; 64KB LDS).
// Best for thin-epilogue GEMMs (sim/pv). 256 thr = 4 waves (2x2).
// ============================================================================
template <typename F>
DEV void gemm_tile(const ushort_t* A, int lda, const ushort_t* B, int ldb, int K, F&& epi) {
  __shared__ alignas(16) ushort_t As[2][128 * 64];
  __shared__ alignas(16) ushort_t Bs[2][128 * 64];
  int t = threadIdx.x;
  int lane = t & 63;
  int w = t >> 6;
  int wr = w >> 1, wc = w & 1;
  const int nk = K >> 6;
  f32x4 acc[4][4];
#pragma unroll
  for (int m = 0; m < 4; ++m)
#pragma unroll
    for (int n = 0; n < 4; ++n) acc[m][n] = (f32x4){0.f, 0.f, 0.f, 0.f};

  int aoff[4][2], boff[4][2];
#pragma unroll
  for (int m = 0; m < 4; ++m)
#pragma unroll
    for (int kk = 0; kk < 2; ++kk) {
      int ks = kk * 4 + (lane >> 4);
      aoff[m][kk] = (wr * 64 + m * 16 + (lane & 15)) * 64 + ((ks ^ (lane & 7)) * 8);
      boff[m][kk] = (wc * 64 + m * 16 + (lane & 15)) * 64 + ((ks ^ (lane & 7)) * 8);
    }

  stage_sw(A, lda, As[0], t);
  stage_sw(B, ldb, Bs[0], t);

  for (int kt = 0; kt < nk; ++kt) {
    int cur = kt & 1;
    int nxt = (kt + 1 < nk) ? kt + 1 : kt;
    stage_sw(A + (size_t)nxt * 64, lda, As[cur ^ 1], t);
    stage_sw(B + (size_t)nxt * 64, ldb, Bs[cur ^ 1], t);
    asm volatile("s_waitcnt vmcnt(8)" ::: "memory");
    __builtin_amdgcn_s_barrier();
    __builtin_amdgcn_sched_barrier(0);
    const ushort_t* asb = &As[cur][0];
    const ushort_t* bsb = &Bs[cur][0];
#pragma unroll
    for (int kk = 0; kk < 2; ++kk) {
      bf16x8 af[4], bfr[4];
#pragma unroll
      for (int m = 0; m < 4; ++m) af[m] = *(const bf16x8*)&asb[aoff[m][kk]];
#pragma unroll
      for (int n = 0; n < 4; ++n) bfr[n] = *(const bf16x8*)&bsb[boff[n][kk]];
      __builtin_amdgcn_s_setprio(1);
#pragma unroll
      for (int m = 0; m < 4; ++m)
#pragma unroll
        for (int n = 0; n < 4; ++n)
          acc[m][n] = __builtin_amdgcn_mfma_f32_16x16x32_bf16(af[m], bfr[n], acc[m][n], 0, 0, 0);
      __builtin_amdgcn_s_setprio(0);
    }
    __builtin_amdgcn_s_barrier();
  }

#pragma unroll
  for (int m = 0; m < 4; ++m)
#pragma unroll
    for (int n = 0; n < 4; ++n)
#pragma unroll
      for (int r = 0; r < 4; ++r) {
        int lr = wr * 64 + m * 16 + (lane >> 4) * 4 + r;
        int lc = wc * 64 + n * 16 + (lane & 15);
        epi(lr, lc, acc[m][n][r]);
      }
}

// ============================================================================
// 256x256 8-phase GEMM (T2+T3/T4+T5) — ff2 (K=2048, nk=32), proven.
// ============================================================================
#define MFMA_QUAD(QM, QN)                                                      \
  _Pragma("unroll") for (int m_ = 0; m_ < 4; ++m_)                             \
  _Pragma("unroll") for (int n_ = 0; n_ < 2; ++n_)                             \
  _Pragma("unroll") for (int kk_ = 0; kk_ < 2; ++kk_)                          \
    acc[QM][QN][m_][n_] = __builtin_amdgcn_mfma_f32_16x16x32_bf16(             \
        aF[m_][kk_], bF[QN][n_][kk_], acc[QM][QN][m_][n_], 0, 0, 0);

template <typename F>
DEV void gemm256(const ushort_t* A, int lda, const ushort_t* B, int ldb, int K, F&& epi) {
  __shared__ alignas(16) ushort_t As[2][256 * 64];
  __shared__ alignas(16) ushort_t Bs[2][256 * 64];
  const int tid = threadIdx.x;
  const int lane = tid & 63;
  const int w = tid >> 6;
  const int ur = w >> 2, uc = w & 3;
  const int nk = K >> 6;

  const int c0 = tid, c1 = 512 + tid;
  const int row0 = c0 >> 3, row1 = c1 >> 3;
  const int sw0 = ((c0 & 7) ^ (row0 & 7)) * 8;
  const int sw1 = ((c1 & 7) ^ (row1 & 7)) * 8;
  const ushort_t* Ab0 = A + (size_t)row0 * lda + sw0;
  const ushort_t* Ab1 = A + (size_t)row1 * lda + sw1;
  const ushort_t* Bb0 = B + (size_t)row0 * ldb + sw0;
  const ushort_t* Bb1 = B + (size_t)row1 * ldb + sw1;
  const int ld0 = (0 * 512 + w * 64) * 8;
  const int ld1 = (1 * 512 + w * 64) * 8;

  auto stageA = [&](int t, int hh, int b) {
    const ushort_t* g0 = Ab0 + (size_t)hh * 128 * lda + t * 64;
    const ushort_t* g1 = Ab1 + (size_t)hh * 128 * lda + t * 64;
    ushort_t* l = &As[b][hh * 8192];
    gload16(g0, l + ld0);
    gload16(g1, l + ld1);
  };
  auto stageB = [&](int t, int hh, int b) {
    const ushort_t* g0 = Bb0 + (size_t)hh * 128 * ldb + t * 64;
    const ushort_t* g1 = Bb1 + (size_t)hh * 128 * ldb + t * 64;
    ushort_t* l = &Bs[b][hh * 8192];
    gload16(g0, l + ld0);
    gload16(g1, l + ld1);
  };

  int aoff[4][2], boff[2][2];
#pragma unroll
  for (int m = 0; m < 4; ++m)
#pragma unroll
    for (int kk = 0; kk < 2; ++kk) {
      int row = ur * 64 + m * 16 + (lane & 15);
      int ks = kk * 4 + (lane >> 4);
      aoff[m][kk] = row * 64 + ((ks ^ (lane & 7)) * 8);
    }
#pragma unroll
  for (int n = 0; n < 2; ++n)
#pragma unroll
    for (int kk = 0; kk < 2; ++kk) {
      int row = uc * 32 + n * 16 + (lane & 15);
      int ks = kk * 4 + (lane >> 4);
      boff[n][kk] = row * 64 + ((ks ^ (lane & 7)) * 8);
    }

  f32x4 acc[2][2][4][2];
#pragma unroll
  for (int qm = 0; qm < 2; ++qm)
#pragma unroll
    for (int qn = 0; qn < 2; ++qn)
#pragma unroll
      for (int m = 0; m < 4; ++m)
#pragma unroll
        for (int n = 0; n < 2; ++n) acc[qm][qn][m][n] = (f32x4){0.f, 0.f, 0.f, 0.f};

  stageA(0, 0, 0);
  stageB(0, 0, 0);
  stageB(0, 1, 0);
  stageA(0, 1, 0);
  stageA(1, 0, 1);
  stageB(1, 0, 1);
  asm volatile("s_waitcnt vmcnt(8)" ::: "memory");
  __builtin_amdgcn_s_barrier();

  bf16x8 aF[4][2], bF[2][2][2];

  for (int t = 0; t < nk; ++t) {
    const int b = t & 1;
    const ushort_t* asb = &As[b][0];
    const ushort_t* bsb = &Bs[b][0];
    const int t1 = (t + 1 < nk) ? t + 1 : nk - 1;
    const int t2 = (t + 2 < nk) ? t + 2 : nk - 1;

    // phase 0
#pragma unroll
    for (int m = 0; m < 4; ++m)
#pragma unroll
      for (int kk = 0; kk < 2; ++kk) aF[m][kk] = *(const bf16x8*)&asb[aoff[m][kk]];
#pragma unroll
    for (int n = 0; n < 2; ++n)
#pragma unroll
      for (int kk = 0; kk < 2; ++kk) bF[0][n][kk] = *(const bf16x8*)&bsb[boff[n][kk]];
    stageB(t1, 1, (t + 1) & 1);
    __builtin_amdgcn_s_barrier();
    asm volatile("s_waitcnt lgkmcnt(0)" ::: "memory");
    __builtin_amdgcn_s_setprio(1);
    MFMA_QUAD(0, 0)
    __builtin_amdgcn_s_setprio(0);
    asm volatile("s_waitcnt vmcnt(8)" ::: "memory");
    __builtin_amdgcn_s_barrier();

    // phase 1
#pragma unroll
    for (int n = 0; n < 2; ++n)
#pragma unroll
      for (int kk = 0; kk < 2; ++kk) bF[1][n][kk] = *(const bf16x8*)&bsb[boff[n][kk] + 8192];
    stageA(t1, 1, (t + 1) & 1);
    __builtin_amdgcn_s_barrier();
    asm volatile("s_waitcnt lgkmcnt(0)" ::: "memory");
    __builtin_amdgcn_s_setprio(1);
    MFMA_QUAD(0, 1)
    __builtin_amdgcn_s_setprio(0);
    asm volatile("s_waitcnt vmcnt(8)" ::: "memory");
    __builtin_amdgcn_s_barrier();

    // phase 2
#pragma unroll
    for (int m = 0; m < 4; ++m)
#pragma unroll
      for (int kk = 0; kk < 2; ++kk) aF[m][kk] = *(const bf16x8*)&asb[aoff[m][kk] + 8192];
    stageA(t2, 0, b);
    __builtin_amdgcn_s_barrier();
    asm volatile("s_waitcnt lgkmcnt(0)" ::: "memory");
    __builtin_amdgcn_s_setprio(1);
    MFMA_QUAD(1, 0)
    __builtin_amdgcn_s_setprio(0);
    __builtin_amdgcn_s_barrier();

    // phase 3
    stageB(t2, 0, b);
    __builtin_amdgcn_s_barrier();
    __builtin_amdgcn_s_setprio(1);
    MFMA_QUAD(1, 1)
    __builtin_amdgcn_s_setprio(0);
    asm volatile("s_waitcnt vmcnt(8)" ::: "memory");
    __builtin_amdgcn_s_barrier();
  }
  asm volatile("s_waitcnt vmcnt(0)" ::: "memory");

#pragma unroll
  for (int qm = 0; qm < 2; ++qm)
#pragma unroll
    for (int qn = 0; qn < 2; ++qn)
#pragma unroll
      for (int m = 0; m < 4; ++m)
#pragma unroll
        for (int n = 0; n < 2; ++n)
#pragma unroll
          for (int r = 0; r < 4; ++r) {
            int lr = qm * 128 + ur * 64 + m * 16 + (lane >> 4) * 4 + r;
            int lc = qn * 128 + uc * 32 + n * 16 + (lane & 15);
            epi(lr, lc, acc[qm][qn][m][n][r]);
          }
}

// ---------------- FF layer 1: plain 128^2 tile + PAIRED-COLUMN packed epilogue ------------------
// w1_bf rows are PERMUTED within 32-row groups (cvt_w1_kernel): staged pos p holds orig row
// (p&~31) + 2*(p&15) + ((p>>4)&1). Fragment pair (n=2q, n=2q+1) then gives lane j the
// ORIGINAL adjacent columns (base+q*32+2j, +1) -> one packed dword store into h (orig order).
__global__ __launch_bounds__(256) void ff1_kernel(
    int g0, const ushort_t* tokens, const ushort_t* levels_bf, const ushort_t* levels_pos,
    const ushort_t* w1_bf, const float* bu_b1, const float* td_b1, ushort_t* h) {
  int g = g0 + blockIdx.z;
  int tm = blockIdx.x, tn = blockIdx.y;
  const ushort_t* A; int lda;
  if (g == 0)      { A = tokens     + (size_t)tm * 128 * 512;                              lda = 512;  }
  else if (g < 6)  { A = levels_bf  + (size_t)tm * 128 * 3072 + (size_t)(g - 1) * 512;     lda = 3072; }
  else             { A = levels_pos + (size_t)tm * 128 * 2560 + (size_t)(g - 6) * 512;     lda = 2560; }
  const ushort_t* W = w1_bf + (size_t)g * 2048 * 512 + (size_t)tn * 128 * 512;
  const float* bias = (g < 6) ? (bu_b1 + (size_t)g * 2048) : (td_b1 + (size_t)(g - 6) * 2048);
  ushort_t* out = h + ((size_t)(g - g0) * 4096 + (size_t)tm * 128) * 2048 + (size_t)tn * 128;
  gemm_tileP(A, lda, W, 512, 512, [&](int wr, int wc, int lane, f32x4 (&acc)[4][4]) {
#pragma unroll
    for (int m = 0; m < 4; ++m)
#pragma unroll
      for (int q = 0; q < 2; ++q) {
        int col = wc * 64 + q * 32 + 2 * (lane & 15);      // original column (even)
        float b0 = bias[tn * 128 + col];
        float b1 = bias[tn * 128 + col + 1];
#pragma unroll
        for (int r = 0; r < 4; ++r) {
          int lr = wr * 64 + m * 16 + (lane >> 4) * 4 + r;
          float x0 = gelu_f(acc[m][2 * q][r] + b0);
          float x1 = gelu_f(acc[m][2 * q + 1][r] + b1);
          unsigned int pk = (unsigned int)f2bf(x0) | ((unsigned int)f2bf(x1) << 16);
          *(unsigned int*)&out[(size_t)lr * 2048 + col] = pk;
        }
      }
  });
}

// ---------------- FF layer 2: h(2048) -> 512, 8-phase, fused bias, accumulate into levels -------
// RACE GUARD: one ff2 launch must never contain both group g and g+6 (both
// accumulate the SAME level l). Contiguous ranges of length <= 6 are safe.
__global__ __launch_bounds__(512, 2) void ff2_kernel(
    int g0, const ushort_t* h, const ushort_t* w2_bf, const float* bu_b2, const float* td_b2,
    float* levels) {
  int g = g0 + blockIdx.z;
  int tm = blockIdx.x, tn = blockIdx.y;
  const ushort_t* A = h + ((size_t)(g - g0) * 4096 + (size_t)tm * 256) * 2048;
  const ushort_t* W = w2_bf + (size_t)g * 512 * 2048 + (size_t)tn * 256 * 2048;
  int l = (g < 6) ? g : (g - 6);
  const float* bias = (g < 6) ? (bu_b2 + (size_t)g * 512) : (td_b2 + (size_t)(g - 6) * 512);
  gemm256(A, 2048, W, 2048, 2048, [&](int lr, int lc, float v) {
    int bn = tm * 256 + lr;
    int d  = tn * 256 + lc;
    size_t idx = ((size_t)bn * 6 + l) * 512 + d;
    levels[idx] += v + bias[d];
  });
}

// ---------------- SIM: pipelined tile, fused inv-norm column scale + diag mask -> bf16 ----------
__global__ __launch_bounds__(256) void sim_kernel(const ushort_t* levels_bf, const float* invn,
                                                  ushort_t* simattn) {
  int bl = blockIdx.z; int tm = blockIdx.x, tn = blockIdx.y;
  int b = bl / 6, l = bl % 6;
  const ushort_t* A = levels_bf + ((size_t)(b * 256 + tm * 128) * 6 + l) * 512;
  const ushort_t* B = levels_bf + ((size_t)(b * 256 + tn * 128) * 6 + l) * 512;
  const float* inv = invn + (size_t)bl * 256;
  ushort_t* out = simattn + ((size_t)bl * 256 + tm * 128) * 256 + (size_t)tn * 128;
  gemm_tile(A, 3072, B, 3072, 512, [&](int lr, int lc, float v) {
    int i = tm * 128 + lr, j = tn * 128 + lc;
    float s = (i == j) ? -0.0005f : v * inv[j] * 0.044194173824159216f;
    out[(size_t)lr * 256 + lc] = f2bf(s);
  });
}

// ---------------- softmax over 256-wide rows of simattn, in place (bf16) ----------------
__global__ __launch_bounds__(256) void softmax_kernel(ushort_t* simattn) {
  int row = blockIdx.x, t = threadIdx.x;
  __shared__ float red[256];
  float x = bf2f(simattn[(size_t)row * 256 + t]);
  red[t] = x;
  __syncthreads();
  for (int s = 128; s > 0; s >>= 1) { if (t < s) red[t] = fmaxf(red[t], red[t + s]); __syncthreads(); }
  float mx = red[0];
  __syncthreads();
  float e = __expf(x - mx);
  red[t] = e;
  __syncthreads();
  for (int s = 128; s > 0; s >>= 1) { if (t < s) red[t] += red[t + s]; __syncthreads(); }
  float den = red[0];
  simattn[(size_t)row * 256 + t] = f2bf(e / den);
}

// ---------------- PV: pipelined tile; levels += attn * levels_snapshot (f32) ----------------
__global__ __launch_bounds__(256) void pv_kernel(const ushort_t* attn, const ushort_t* levelsT,
                                                 float* levels) {
  int bl = blockIdx.z; int tm = blockIdx.x, tn = blockIdx.y;
  int b = bl / 6, l = bl % 6;
  const ushort_t* A = attn + (size_t)bl * 256 * 256 + (size_t)tm * 128 * 256;
  const ushort_t* B = levelsT + ((size_t)bl * 512 + (size_t)tn * 128) * 256;
  gemm_tile(A, 256, B, 256, 256, [&](int lr, int lc, float v) {
    int n = tm * 128 + lr;
    int d = tn * 128 + lc;
    size_t idx = (((size_t)b * 256 + n) * 6 + l) * 512 + d;
    levels[idx] += v;
  });
}

// ---- prep (+fused contrib scale): levels -> scaled levels, levels_bf, levels_pos, inv-norms ----
__global__ __launch_bounds__(128) void prep_kernel(float* levels, const float* pos_emb,
                                                   ushort_t* levels_bf, ushort_t* levels_pos,
                                                   float* invn, int apply) {
  int bid = blockIdx.x;           // (b*256+n)*6 + l
  int l = bid % 6;
  int bn = bid / 6;
  int n = bn & 255, b = bn >> 8;
  int t = threadIdx.x;
  float4 lv = *(const float4*)&levels[(size_t)bid * 512 + t * 4];
  if (apply) {
    float rc = (l == 5) ? (1.0f / 3.0f) : 0.25f;
    lv.x *= rc; lv.y *= rc; lv.z *= rc; lv.w *= rc;
    *(float4*)&levels[(size_t)bid * 512 + t * 4] = lv;   // write back scaled state
  }
  float ss = lv.x * lv.x + lv.y * lv.y + lv.z * lv.z + lv.w * lv.w;
#pragma unroll
  for (int off = 32; off > 0; off >>= 1) ss += __shfl_down(ss, off);
  __shared__ float s2[2];
  if ((t & 63) == 0) s2[t >> 6] = ss;
  __syncthreads();
  if (t == 0) {
    float tot = s2[0] + s2[1];
    invn[(size_t)(b * 6 + l) * 256 + n] = 1.0f / fmaxf(sqrtf(tot), 1e-12f);
  }
  ushort4 o;
  o.x = f2bf(lv.x); o.y = f2bf(lv.y); o.z = f2bf(lv.z); o.w = f2bf(lv.w);
  *(ushort4*)&levels_bf[(size_t)bid * 512 + t * 4] = o;
  if (l >= 1) {
    float4 pu = *(const float4*)&pos_emb[(size_t)n * 512 + t * 4];
    ushort4 op;
    op.x = f2bf(lv.x + pu.x);
    op.y = f2bf(lv.y + pu.y);
    op.z = f2bf(lv.z + pu.z);
    op.w = f2bf(lv.w + pu.w);
    *(ushort4*)&levels_pos[((size_t)bn * 5 + (l - 1)) * 512 + t * 4] = op;
  }
}

// ---------------- transpose: levels f32 (b,n,l,d) -> levelsT bf16 (b,l,d,n) ----------------
__global__ __launch_bounds__(256) void transpose_kernel(const float* levels, ushort_t* levelsT) {
  int bl = blockIdx.z; int b = bl / 6, l = bl % 6;
  int n0 = blockIdx.y * 64, d0 = blockIdx.x * 64;
  __shared__ ushort_t tile[64][72];
  int t = threadIdx.x;
#pragma unroll
  for (int rr = 0; rr < 2; ++rr) {
    int c = t + rr * 256;
    int r = c >> 3, c8 = (c & 7) * 8;
    const float* src = &levels[(((size_t)(b * 256 + n0 + r)) * 6 + l) * 512 + d0 + c8];
    float4 v0 = *(const float4*)src;
    float4 v1 = *(const float4*)(src + 4);
    tile[r][c8 + 0] = f2bf(v0.x); tile[r][c8 + 1] = f2bf(v0.y);
    tile[r][c8 + 2] = f2bf(v0.z); tile[r][c8 + 3] = f2bf(v0.w);
    tile[r][c8 + 4] = f2bf(v1.x); tile[r][c8 + 5] = f2bf(v1.y);
    tile[r][c8 + 6] = f2bf(v1.z); tile[r][c8 + 7] = f2bf(v1.w);
  }
  __syncthreads();
#pragma unroll
  for (int rr = 0; rr < 2; ++rr) {
    int c = t + rr * 256;
    int dr = c >> 3, n8 = (c & 7) * 8;
    ushort4 o0, o1;
    o0.x = tile[n8 + 0][dr]; o0.y = tile[n8 + 1][dr]; o0.z = tile[n8 + 2][dr]; o0.w = tile[n8 + 3][dr];
    o1.x = tile[n8 + 4][dr]; o1.y = tile[n8 + 5][dr]; o1.z = tile[n8 + 6][dr]; o1.w = tile[n8 + 7][dr];
    ushort_t* dst = &levelsT[((size_t)bl * 512 + d0 + dr) * 256 + n0 + n8];
    *(ushort4*)dst = o0;
    *(ushort4*)(dst + 4) = o1;
  }
}

// ---------------- patch embed: img(f32) -> tokens bf16 (4096 x 512) ----------------
__global__ __launch_bounds__(256) void tokens_kernel(const float* img, const float* ttw,
                                                     const float* ttb, ushort_t* tokens) {
  int token = blockIdx.x;
  int b = token >> 8, n = token & 255;
  int ph = n >> 4, pw = n & 15;
  __shared__ float patch[196];
  int t = threadIdx.x;
  if (t < 196) {
    int r = t / 14, cc = t % 14;
    patch[t] = img[(size_t)b * 50176 + (size_t)(ph * 14 + r) * 224 + pw * 14 + cc];
  }
  __syncthreads();
  float a0 = ttb[t];
  float a1 = ttb[t + 256];
  for (int k = 0; k < 196; ++k) {
    float p = patch[k];
    a0 += p * ttw[(size_t)k * 512 + t];
    a1 += p * ttw[(size_t)k * 512 + t + 256];
  }
  tokens[(size_t)token * 512 + t]       = f2bf(a0);
  tokens[(size_t)token * 512 + t + 256] = f2bf(a1);
}

// ---------------- init: broadcast init_levels(f32) -> levels f32 (d_out) ----------------
__global__ void init_kernel(const float* init_levels, float* levels) {
  size_t i4 = (size_t)blockIdx.x * 256 + threadIdx.x;
  size_t e0 = i4 * 4;
  int idx = (int)(e0 % 3072);
  *(float4*)&levels[e0] = *(const float4*)&init_levels[idx];
}

// ---------------- scale: levels *= 1/contrib[l], in place (final iteration only) ----------------
__global__ void scale_kernel(float* levels) {
  size_t i4 = (size_t)blockIdx.x * 256 + threadIdx.x;
  size_t e0 = i4 * 4;
  int l = (int)((e0 >> 9) % 6);
  float rc = (l == 5) ? (1.0f / 3.0f) : 0.25f;
  float4 a = *(const float4*)&levels[e0];
  float4 o = {a.x * rc, a.y * rc, a.z * rc, a.w * rc};
  *(float4*)&levels[e0] = o;
}

// ---------------- cvt: f32 -> bf16, 4 elems/thread (plain, for w2) ----------------
__global__ void cvt_kernel(const float* src, ushort_t* dst, int n4) {
  int i = blockIdx.x * 256 + threadIdx.x;
  if (i >= n4) return;
  float4 v = ((const float4*)src)[i];
  ushort4 o;
  o.x = f2bf(v.x); o.y = f2bf(v.y); o.z = f2bf(v.z); o.w = f2bf(v.w);
  ((ushort4*)dst)[i] = o;
}

// ---- cvt for w1: f32 -> bf16 with ROW PERMUTATION within 32-row groups ----
// staged row p = (r & ~31) | ((r&1)<<4) | ((r&31)>>1)  (rows = w1 output cols, 512-wide)
__global__ void cvt_w1_kernel(const float* src, ushort_t* dst, int nrows) {
  int i = blockIdx.x * 256 + threadIdx.x;          // one float4 (4 cols) per thread
  if (i >= nrows * 128) return;
  int row = i >> 7, k4 = (i & 127) * 4;
  int grp = row >> 11, rr = row & 2047;            // 2048 rows per group
  int p = (rr & ~31) | ((rr & 1) << 4) | ((rr & 31) >> 1);
  float4 v = *(const float4*)&src[(size_t)row * 512 + k4];
  ushort4 o;
  o.x = f2bf(v.x); o.y = f2bf(v.y); o.z = f2bf(v.z); o.w = f2bf(v.w);
  *(ushort4*)&dst[((size_t)(grp << 11) + p) * 512 + k4] = o;
}

extern "C" void kernel_launch(void* const* d_in, const int* in_sizes, int n_in,
                              void* d_out, int out_size, void* d_ws, size_t ws_size,
                              hipStream_t stream) {
  const float* img    = (const float*)d_in[0];
  const float* ttw    = (const float*)d_in[1];
  const float* ttb    = (const float*)d_in[2];
  const float* pos    = (const float*)d_in[3];
  const float* initlv = (const float*)d_in[4];
  const float* bu_w1  = (const float*)d_in[5];
  const float* bu_b1  = (const float*)d_in[6];
  const float* bu_w2  = (const float*)d_in[7];
  const float* bu_b2  = (const float*)d_in[8];
  const float* td_w1  = (const float*)d_in[9];
  const float* td_b1  = (const float*)d_in[10];
  const float* td_w2  = (const float*)d_in[11];
  const float* td_b2  = (const float*)d_in[12];

  float* levels = (float*)d_out;   // (b,n,6,512) f32 state lives in d_out

  const size_t HB = 16777216ull;   // bytes per h group (4096x2048 bf16)

  char* p = (char*)d_ws;
  auto alloc = [&](size_t bytes) { char* r = p; p += (bytes + 255) & ~(size_t)255; return r; };
  float*    invn       = (float*)alloc(24576ull * 4);
  ushort_t* tokens     = (ushort_t*)alloc(2097152ull * 2);
  ushort_t* levels_bf  = (ushort_t*)alloc(12582912ull * 2);
  ushort_t* levels_pos = (ushort_t*)alloc(10485760ull * 2);
  ushort_t* levelsT    = (ushort_t*)alloc(12582912ull * 2);
  ushort_t* simattn    = (ushort_t*)alloc(6291456ull * 2);
  ushort_t* w1_bf      = (ushort_t*)alloc(11534336ull * 2);
  ushort_t* w2_bf      = (ushort_t*)alloc(11534336ull * 2);
  size_t used = (size_t)(p - (char*)d_ws);
  if (used + HB > ws_size) return;                 // can't fit even 1-group h
  int gpp = (int)((ws_size - used) / HB);          // groups per FF pass
  if (gpp > 6) gpp = 6;                            // <=6 contiguous: no g/g+6 race
  ushort_t* h = (ushort_t*)alloc((size_t)gpp * HB);

  cvt_w1_kernel<<<6144, 256, 0, stream>>>(bu_w1, w1_bf, 12288);
  cvt_w1_kernel<<<5120, 256, 0, stream>>>(td_w1, w1_bf + 6291456ull, 10240);
  cvt_kernel<<<6144, 256, 0, stream>>>(bu_w2, w2_bf, 1572864);
  cvt_kernel<<<5120, 256, 0, stream>>>(td_w2, w2_bf + 6291456ull, 1310720);
  tokens_kernel<<<4096, 256, 0, stream>>>(img, ttw, ttb, tokens);
  init_kernel<<<12288, 256, 0, stream>>>(initlv, levels);

  for (int it = 0; it < 12; ++it) {
    // scale of the previous iteration's accumulation is fused into prep (apply=1)
    prep_kernel<<<24576, 128, 0, stream>>>(levels, pos, levels_bf, levels_pos, invn,
                                           it > 0 ? 1 : 0);
    transpose_kernel<<<dim3(8, 4, 96), 256, 0, stream>>>(levels, levelsT);
    sim_kernel<<<dim3(2, 2, 96), 256, 0, stream>>>(levels_bf, invn, simattn);
    softmax_kernel<<<24576, 256, 0, stream>>>(simattn);
    pv_kernel<<<dim3(2, 4, 96), 256, 0, stream>>>(simattn, levelsT, levels);
    for (int g0 = 0; g0 < 11; g0 += gpp) {
      int gn = 11 - g0 < gpp ? 11 - g0 : gpp;
      ff1_kernel<<<dim3(32, 16, gn), 256, 0, stream>>>(g0, tokens, levels_bf, levels_pos,
                                                       w1_bf, bu_b1, td_b1, h);
      ff2_kernel<<<dim3(16, 2, gn), 512, 0, stream>>>(g0, h, w2_bf, bu_b2, td_b2, levels);
    }
  }
  scale_kernel<<<12288, 256, 0, stream>>>(levels);   // final contrib division
}